// Round 3
// baseline (4162.695 us; speedup 1.0000x reference)
//
#include <hip/hip_runtime.h>
#include <math.h>

// EBT_GRC beam-search forward, round 14: counted-vmcnt deep prefetch (T4).
// Round-13 profile: k_gemm 56us at 4.3x MFMA floor, MfmaUtil 21%, VALU 14%,
// HBM 21% -> every K-step serially eats a load round-trip at the barrier's
// implicit vmcnt(0). Replace __syncthreads with raw s_barrier + counted
// s_waitcnt vmcnt(N) (never 0 in steady state) + deeper LDS rings:
//   k_gemm:  4 x 32KB ring (128KB LDS), depth-3, vmcnt(16); 1 blk/CU
//   k_gemm1: 3 x 24KB ring ( 72KB LDS), depth-2, vmcnt(6);  2 blk/CU
//   k_wscore:3 x 16KB ring ( 48KB LDS), depth-2, vmcnt(4);  2 blk/CU
// Safety: one barrier/iter; STAGE(it+D) issued after barrier overwrites the
// buffer whose reads finished in iter it-1 (lgkm drained by MFMA data deps).
// N=256, S=32, D=512, CH=2048, BEAM=5. WS ~185 MB.

#define NN   256
#define S0   32
#define WDIM 512
#define DD   512
#define CHID 2048
#define BEAM 5
#define NB   (NN*BEAM)   // 1280
#define RSCALE 2048.0f
#define RINV  (1.0f/2048.0f)
#define AR_INIT 8192
#define AR_TOT  (AR_INIT + 30*NB)    // 46592 rows
#define MN2 ((size_t)NB*CHID)        // partial-buffer slice stride

typedef __attribute__((ext_vector_type(8))) _Float16 f16x8;
typedef __attribute__((ext_vector_type(4))) float f32x4;

__device__ __forceinline__ float gelu_f(float x) {
    return 0.5f * x * (1.0f + erff(x * 0.7071067811865475f));
}
__device__ __forceinline__ _Float16 hi16(float v) { return (_Float16)v; }
__device__ __forceinline__ _Float16 lo16(float v, _Float16 h) {
    return (_Float16)((v - (float)h) * RSCALE);
}
__device__ __forceinline__ float recon(_Float16 h, _Float16 l) {
    return (float)h + RINV * (float)l;
}

__device__ __forceinline__ void gload_lds16(const void* g, void* l) {
    __builtin_amdgcn_global_load_lds(
        (const __attribute__((address_space(1))) unsigned*)g,
        (__attribute__((address_space(3))) unsigned*)l, 16, 0, 0);
}

// raw barrier that also blocks compiler memory reordering (s_barrier alone
// is NOT an IR memory fence; the "memory" clobber makes it one here)
__device__ __forceinline__ void barrier_mem() {
    asm volatile("s_barrier" ::: "memory");
}
template<int N>
__device__ __forceinline__ void wait_vmcnt() {
    asm volatile("s_waitcnt vmcnt(%0)" :: "i"(N) : "memory");
}

__device__ __forceinline__ float block_reduce_sum(float v, float* sb) {
    #pragma unroll
    for (int o = 32; o > 0; o >>= 1) v += __shfl_down(v, o);
    const int lane = threadIdx.x & 63, wid = threadIdx.x >> 6;
    __syncthreads();
    if (lane == 0) sb[wid] = v;
    __syncthreads();
    return sb[0] + sb[1] + sb[2] + sb[3];
}

// ========= fp16x2 split MFMA GEMM, split-K, 4-deep LDS ring =========
template<int AIDX>
__global__ __launch_bounds__(256, 1) void k_gemm(
    const _Float16* __restrict__ Ah, const _Float16* __restrict__ Al,
    const _Float16* __restrict__ Bh, const _Float16* __restrict__ Bl,
    const float* __restrict__ bias, float* __restrict__ Cf,
    int M, int N, int Ktot, int Kchunk)
{
    __shared__ __align__(16) _Float16 lds[4][4 * 4096];   // 128 KB ring
    const int t = threadIdx.x, wave = t >> 6, lane = t & 63;
    const int bm = blockIdx.y * 128, bn = blockIdx.x * 128;
    const int koff = blockIdx.z * Kchunk;
    const int wm = (wave >> 1) * 64, wn = (wave & 1) * 64;
    const int rsub = lane >> 2, seg = lane & 3;
    const int fm = lane & 15, fko = (lane >> 4) * 8;

    f32x4 acc0[4][4], acc1[4][4];
    #pragma unroll
    for (int i = 0; i < 4; ++i)
        #pragma unroll
        for (int j = 0; j < 4; ++j) {
            acc0[i][j] = (f32x4){0.f, 0.f, 0.f, 0.f};
            acc1[i][j] = (f32x4){0.f, 0.f, 0.f, 0.f};
        }

    const int iters = Kchunk >> 5;
    // 8 global_load_lds per wave per stage
    #define STAGE_G(IT, BUF) {                                                 \
        const int k = koff + (IT)*32;                                          \
        _Float16* Lb = &lds[BUF][0];                                           \
        _Pragma("unroll")                                                      \
        for (int j = 0; j < 2; ++j) {                                          \
            const int q = wave * 2 + j;                                        \
            const size_t aoff = (size_t)(bm + q*16 + rsub) * Ktot + k + seg*8; \
            const size_t boff = (size_t)(bn + q*16 + rsub) * Ktot + k + seg*8; \
            gload_lds16(Ah + aoff, Lb + 0*4096 + q*512);                       \
            gload_lds16(Al + aoff, Lb + 1*4096 + q*512);                       \
            gload_lds16(Bh + boff, Lb + 2*4096 + q*512);                       \
            gload_lds16(Bl + boff, Lb + 3*4096 + q*512);                       \
        } }

    STAGE_G(0, 0);
    if (1 < iters) STAGE_G(1, 1);
    if (2 < iters) STAGE_G(2, 2);
    for (int it = 0; it < iters; ++it) {
        const int rem = iters - it;
        // wait for tile it only: tiles it+1, it+2 stay in flight (8 loads each)
        if (rem > 2)      wait_vmcnt<16>();
        else if (rem == 2) wait_vmcnt<8>();
        else              wait_vmcnt<0>();
        barrier_mem();
        if (it + 3 < iters) STAGE_G(it + 3, (it + 3) & 3);
        const _Float16* L = &lds[it & 3][0];
        f16x8 ah[4], al[4];
        #pragma unroll
        for (int i = 0; i < 4; ++i) {
            const int ar = wm + i*16 + fm;
            ah[i] = *(const f16x8*)&L[0*4096 + ar*32 + fko];
            al[i] = *(const f16x8*)&L[1*4096 + ar*32 + fko];
        }
        #pragma unroll
        for (int j = 0; j < 4; ++j) {
            const int br = wn + j*16 + fm;
            f16x8 bh = *(const f16x8*)&L[2*4096 + br*32 + fko];
            f16x8 bl = *(const f16x8*)&L[3*4096 + br*32 + fko];
            #pragma unroll
            for (int i = 0; i < 4; ++i) {
                acc0[i][j] = __builtin_amdgcn_mfma_f32_16x16x32_f16(ah[i], bh, acc0[i][j], 0, 0, 0);
                acc1[i][j] = __builtin_amdgcn_mfma_f32_16x16x32_f16(ah[i], bl, acc1[i][j], 0, 0, 0);
                acc1[i][j] = __builtin_amdgcn_mfma_f32_16x16x32_f16(al[i], bh, acc1[i][j], 0, 0, 0);
            }
        }
    }
    float* dst = Cf + (size_t)blockIdx.z * M * N;
    #pragma unroll
    for (int i = 0; i < 4; ++i)
        #pragma unroll
        for (int j = 0; j < 4; ++j) {
            const int col = bn + wn + j*16 + fm;
            const float bv = (blockIdx.z == 0) ? bias[col] : 0.f;
            #pragma unroll
            for (int r = 0; r < 4; ++r) {
                const int row = bm + wm + i*16 + (lane >> 4)*4 + r;
                dst[(size_t)row * N + col] = acc0[i][j][r] + acc1[i][j][r] * RINV + bv;
            }
        }
    #undef STAGE_G
}

// ==== GEMM1 fused: H = gelu(cat@Wc1+bc1) -> fp16 h/l, 3-deep ring ====
template<int AIDX>
__global__ __launch_bounds__(256, 1) void k_gemm1(
    const _Float16* __restrict__ Ah, const _Float16* __restrict__ Al,
    const _Float16* __restrict__ Bh, const _Float16* __restrict__ Bl,
    const float* __restrict__ bias,
    _Float16* __restrict__ Oh, _Float16* __restrict__ Ol,
    const int* __restrict__ lrid, const int* __restrict__ rrid,
    const int* __restrict__ idxt, int N)
{
    __shared__ __align__(16) _Float16 lds[3][12288];   // 72 KB ring
    const int t = threadIdx.x, wave = t >> 6, lane = t & 63;
    const int bm = blockIdx.y * 128, bn = blockIdx.x * 64;
    const int rsub = lane >> 2, seg = lane & 3;
    const int fm = lane & 15, quad = lane >> 4, fko = quad * 8;

    size_t lb[2], rb[2];
    #pragma unroll
    for (int j = 0; j < 2; ++j) {
        const int rowm = bm + (wave*2 + j)*16 + rsub;
        if (AIDX == 1) {
            lb[j] = (size_t)lrid[rowm] * 512;
            rb[j] = (size_t)rrid[rowm] * 512;
        } else {
            lb[j] = (size_t)idxt[rowm*31 + 0] * 512;
            rb[j] = (size_t)idxt[rowm*31 + 1] * 512;
        }
    }
    const size_t bbase = (size_t)(bn + wave*16 + rsub) * 1024;

    f32x4 acc0[2][4], acc1[2][4];
    #pragma unroll
    for (int i = 0; i < 2; ++i)
        #pragma unroll
        for (int j = 0; j < 4; ++j) {
            acc0[i][j] = (f32x4){0.f, 0.f, 0.f, 0.f};
            acc1[i][j] = (f32x4){0.f, 0.f, 0.f, 0.f};
        }

    // 6 global_load_lds per wave per stage
    #define STAGE_G1(IT, BUF) {                                                 \
        const int k0 = (IT)*32;                                                 \
        _Float16* Lb = &lds[BUF][0];                                            \
        _Pragma("unroll")                                                       \
        for (int j = 0; j < 2; ++j) {                                           \
            const int q = wave*2 + j;                                           \
            const size_t aoff = (k0 < 512 ? lb[j] + k0 : rb[j] + (k0-512)) + seg*8; \
            gload_lds16(Ah + aoff, Lb + q*512);                                 \
            gload_lds16(Al + aoff, Lb + 4096 + q*512);                          \
        }                                                                       \
        gload_lds16(Bh + bbase + k0 + seg*8, Lb + 8192 + wave*512);             \
        gload_lds16(Bl + bbase + k0 + seg*8, Lb + 10240 + wave*512); }

    STAGE_G1(0, 0);
    STAGE_G1(1, 1);
    for (int it = 0; it < 32; ++it) {
        if (it < 31) wait_vmcnt<6>();   // tile it done, it+1 in flight
        else         wait_vmcnt<0>();
        barrier_mem();
        if (it + 2 < 32) STAGE_G1(it + 2, (it + 2) % 3);
        const _Float16* L = &lds[it % 3][0];
        f16x8 ah[2], al[2];
        #pragma unroll
        for (int i = 0; i < 2; ++i) {
            const int ar = wave*32 + i*16 + fm;
            ah[i] = *(const f16x8*)&L[ar*32 + fko];
            al[i] = *(const f16x8*)&L[4096 + ar*32 + fko];
        }
        #pragma unroll
        for (int j = 0; j < 4; ++j) {
            const int br = j*16 + fm;
            f16x8 bh = *(const f16x8*)&L[8192 + br*32 + fko];
            f16x8 bl = *(const f16x8*)&L[10240 + br*32 + fko];
            #pragma unroll
            for (int i = 0; i < 2; ++i) {
                acc0[i][j] = __builtin_amdgcn_mfma_f32_16x16x32_f16(ah[i], bh, acc0[i][j], 0, 0, 0);
                acc1[i][j] = __builtin_amdgcn_mfma_f32_16x16x32_f16(ah[i], bl, acc1[i][j], 0, 0, 0);
                acc1[i][j] = __builtin_amdgcn_mfma_f32_16x16x32_f16(al[i], bh, acc1[i][j], 0, 0, 0);
            }
        }
    }
    #pragma unroll
    for (int i = 0; i < 2; ++i)
        #pragma unroll
        for (int j = 0; j < 4; ++j) {
            const int col = bn + j*16 + fm;
            const float bv = bias[col];
            #pragma unroll
            for (int r = 0; r < 4; ++r) {
                const int row = bm + wave*32 + i*16 + quad*4 + r;
                float v = gelu_f(acc0[i][j][r] + acc1[i][j][r] * RINV + bv);
                _Float16 h = hi16(v);
                Oh[(size_t)row * N + col] = h;
                Ol[(size_t)row * N + col] = lo16(v, h);
            }
        }
    #undef STAGE_G1
}

// ====== fused score (64x64 tiles, 3-deep ring): w += gelu(cat@Wd1+bd1)@Wd2 ======
template<int MODE>
__global__ __launch_bounds__(256, 2) void k_wscore(
    const _Float16* __restrict__ ch, const _Float16* __restrict__ cl,
    const int* __restrict__ posb, const int* __restrict__ idxt,
    const _Float16* __restrict__ Bh, const _Float16* __restrict__ Bl,
    const float* __restrict__ bd1, const float* __restrict__ u512,
    const float* __restrict__ bd2, float* __restrict__ w, int Spairs)
{
    __shared__ __align__(16) _Float16 lds[3][8192];   // 48 KB ring
    const int t = threadIdx.x, wave = t >> 6, lane = t & 63;
    const int bm = blockIdx.x * 64, ncol0 = blockIdx.y * 64;
    const int rsub = lane >> 2, seg = lane & 3;
    const int fm = lane & 15, quad = lane >> 4, fko = quad * 8;

    size_t lb, rb;
    {
        const int rowm = bm + wave*16 + rsub;
        int lrow, rrow;
        if (MODE == 0) {
            const int n = rowm / 31, s = rowm - n * 31;
            lrow = n*32 + s; rrow = lrow + 1;
        } else {
            const int nk = rowm >> 1, slot = rowm & 1;
            const int s = posb[nk];
            int jw = s - 1 + slot;
            int jc = jw < 0 ? 0 : (jw > Spairs - 1 ? Spairs - 1 : jw);
            lrow = idxt[nk*31 + jc]; rrow = idxt[nk*31 + jc + 1];
        }
        lb = (size_t)lrow * 512; rb = (size_t)rrow * 512;
    }
    const size_t bbase = (size_t)(ncol0 + wave*16 + rsub) * 1024;

    f32x4 acc0[4], acc1[4];
    #pragma unroll
    for (int j = 0; j < 4; ++j) {
        acc0[j] = (f32x4){0.f, 0.f, 0.f, 0.f};
        acc1[j] = (f32x4){0.f, 0.f, 0.f, 0.f};
    }
    // 4 global_load_lds per wave per stage
    #define STAGE_WS(IT, BUF) {                                                \
        const int k0 = (IT)*32;                                                \
        _Float16* Lb = &lds[BUF][0];                                           \
        const size_t aoff = (k0 < 512 ? lb + k0 : rb + (k0-512)) + seg*8;      \
        gload_lds16(ch + aoff, Lb + 0*2048 + wave*512);                        \
        gload_lds16(cl + aoff, Lb + 1*2048 + wave*512);                        \
        gload_lds16(Bh + bbase + k0 + seg*8, Lb + 2*2048 + wave*512);          \
        gload_lds16(Bl + bbase + k0 + seg*8, Lb + 3*2048 + wave*512); }

    STAGE_WS(0, 0);
    STAGE_WS(1, 1);
    for (int it = 0; it < 32; ++it) {
        if (it < 31) wait_vmcnt<4>();   // tile it done, it+1 in flight
        else         wait_vmcnt<0>();
        barrier_mem();
        if (it + 2 < 32) STAGE_WS(it + 2, (it + 2) % 3);
        const _Float16* L = &lds[it % 3][0];
        const int ar = wave*16 + fm;
        f16x8 ah = *(const f16x8*)&L[0*2048 + ar*32 + fko];
        f16x8 al = *(const f16x8*)&L[1*2048 + ar*32 + fko];
        #pragma unroll
        for (int j = 0; j < 4; ++j) {
            const int br = j*16 + fm;
            f16x8 bh = *(const f16x8*)&L[2*2048 + br*32 + fko];
            f16x8 bl = *(const f16x8*)&L[3*2048 + br*32 + fko];
            acc0[j] = __builtin_amdgcn_mfma_f32_16x16x32_f16(ah, bh, acc0[j], 0, 0, 0);
            acc1[j] = __builtin_amdgcn_mfma_f32_16x16x32_f16(ah, bl, acc1[j], 0, 0, 0);
            acc1[j] = __builtin_amdgcn_mfma_f32_16x16x32_f16(al, bh, acc1[j], 0, 0, 0);
        }
    }
    float part[4] = {0.f, 0.f, 0.f, 0.f};
    #pragma unroll
    for (int j = 0; j < 4; ++j) {
        const int col = ncol0 + j*16 + fm;
        const float bv = bd1[col], uv = u512[col];
        #pragma unroll
        for (int r = 0; r < 4; ++r) {
            float v = acc0[j][r] + acc1[j][r] * RINV + bv;
            part[r] += gelu_f(v) * uv;
        }
    }
    #pragma unroll
    for (int r = 0; r < 4; ++r) {
        float s = part[r];
        s += __shfl_xor(s, 1); s += __shfl_xor(s, 2);
        s += __shfl_xor(s, 4); s += __shfl_xor(s, 8);
        part[r] = s;
    }
    if (fm == 0) {
        const float bd2v = (blockIdx.y == 0) ? bd2[0] : 0.f;
        #pragma unroll
        for (int r = 0; r < 4; ++r) {
            const int rowm = bm + wave*16 + quad*4 + r;
            int wi = -1;
            if (MODE == 0) {
                const int n = rowm / 31, s = rowm - n * 31;
                wi = n * BEAM * S0 + s;
            } else {
                const int nk = rowm >> 1, slot = rowm & 1;
                const int jw = posb[nk] - 1 + slot;
                if (jw >= 0 && jw < Spairs) wi = nk * S0 + jw;
            }
            if (wi >= 0) atomicAdd(&w[wi], part[r] + bd2v);
        }
    }
    #undef STAGE_WS
}

// ============ weight transpose + fp16 split ============
__global__ __launch_bounds__(256) void k_tsplit(
    const float* __restrict__ in, _Float16* __restrict__ oh,
    _Float16* __restrict__ ol, int K, int N)
{
    __shared__ float tile[32][33];
    const int bx = blockIdx.x * 32, by = blockIdx.y * 32;
    const int t = threadIdx.x, r = t >> 5, c = t & 31;
    #pragma unroll
    for (int p = 0; p < 4; ++p)
        tile[r + p*8][c] = in[(size_t)(by + r + p*8) * N + bx + c];
    __syncthreads();
    #pragma unroll
    for (int p = 0; p < 4; ++p) {
        const int nl = r + p*8;
        float v = tile[c][nl];
        _Float16 h = hi16(v);
        oh[(size_t)(bx + nl) * K + by + c] = h;
        ol[(size_t)(bx + nl) * K + by + c] = lo16(v, h);
    }
}

// ============ elementwise fp16 split (x rows, init only) ============
__global__ __launch_bounds__(256) void k_xsplit(
    const float* __restrict__ in, _Float16* __restrict__ oh,
    _Float16* __restrict__ ol)
{
    const size_t i = ((size_t)blockIdx.x * 256 + threadIdx.x) * 4;
    float4 v = *(const float4*)(in + i);
    _Float16 h0 = hi16(v.x), h1 = hi16(v.y), h2 = hi16(v.z), h3 = hi16(v.w);
    typedef __attribute__((ext_vector_type(4))) _Float16 f16x4v;
    f16x4v h = {h0, h1, h2, h3};
    f16x4v l = {lo16(v.x,h0), lo16(v.y,h1), lo16(v.z,h2), lo16(v.w,h3)};
    *(f16x4v*)(oh + i) = h;
    *(f16x4v*)(ol + i) = l;
}

// ============ init layernorm -> split arena rows ============
__global__ __launch_bounds__(256) void k_ln_init(
    const float* __restrict__ y, const float* __restrict__ g,
    const float* __restrict__ b, _Float16* __restrict__ cha,
    _Float16* __restrict__ cla)
{
    const int row = blockIdx.x;
    const float* yr = y + (size_t)row * DD;
    const int t = threadIdx.x;
    float v0 = yr[t], v1 = yr[t + 256];
    __shared__ float sb[8];
    float s1 = block_reduce_sum(v0 + v1, sb);
    float s2 = block_reduce_sum(v0*v0 + v1*v1, sb);
    float mu = s1 * (1.f/512.f);
    float rstd = rsqrtf(s2 * (1.f/512.f) - mu*mu + 1e-5f);
    float a0 = (v0 - mu) * rstd * g[t]       + b[t];
    float a1 = (v1 - mu) * rstd * g[t + 256] + b[t + 256];
    _Float16 h0 = hi16(a0), h1 = hi16(a1);
    cha[(size_t)row*DD + t]       = h0;
    cla[(size_t)row*DD + t]       = lo16(a0, h0);
    cha[(size_t)row*DD + t + 256] = h1;
    cla[(size_t)row*DD + t + 256] = lo16(a1, h1);
}

__global__ void k_init_state(float* accu, float* bm, int* idx0, float* wz) {
    int i = blockIdx.x * blockDim.x + threadIdx.x;
    if (i < NB*S0) wz[i] = 0.f;
    if (i < AR_INIT) idx0[i] = i;
    if (i < NB) { accu[i] = 0.f; bm[i] = 1.f; }
}

// ====== top-k (5 waves: wave b = beam b) + beam select + l/r row ids ======
__global__ __launch_bounds__(320) void k_topk(
    const float* __restrict__ w, const float* __restrict__ accu,
    const float* __restrict__ bmask, const float* __restrict__ maskg,
    int iiter, int B, int S, int topk, int do_bsel,
    const int* __restrict__ idxold, int BAo, int STo,
    int* __restrict__ parent, int* __restrict__ posb,
    int* __restrict__ lrid, int* __restrict__ rrid,
    float* __restrict__ accu_out, float* __restrict__ bm_out,
    float* __restrict__ wnew, int Snew, int dow)
{
    const int n = blockIdx.x, t = threadIdx.x;
    const int wave = t >> 6, lane = t & 63;
    __shared__ int   selpos_s[BEAM][BEAM];
    __shared__ float nscore_s[BEAM][BEAM];
    __shared__ int   par_s[BEAM], pos_s[BEAM];
    const float* mrow = maskg + n*S0 + (iiter + 1);
    const float mk   = (lane < S) ? mrow[lane] : 0.f;
    const float done = 1.f - mrow[0];
    // ---- phase 1: wave b computes beam b's masked softmax + top-k ----
    if (wave < B) {
        const int b = wave;
        float ml;
        if (lane < S) {
            float wv = w[(n*BEAM + b)*S0 + lane];
            ml = (mk > 0.f) ? wv : -1e9f;
        } else ml = -INFINITY;
        float mx = ml;
        #pragma unroll
        for (int o = 32; o > 0; o >>= 1) mx = fmaxf(mx, __shfl_xor(mx, o));
        float e = (lane < S) ? expf(ml - mx) * mk : 0.f;
        float es = e;
        #pragma unroll
        for (int o = 32; o > 0; o >>= 1) es += __shfl_xor(es, o);
        const float den = es + 1e-20f;
        float mlc = ml;
        for (int ts = 0; ts < topk; ++ts) {
            unsigned int fb = __float_as_uint(mlc);
            unsigned int ok = (fb & 0x80000000u) ? ~fb : (fb | 0x80000000u);
            unsigned long long key =
                ((unsigned long long)ok << 32) | (unsigned int)(63 - lane);
            if (lane >= S) key = 0ull;
            unsigned long long km = key;
            #pragma unroll
            for (int o = 32; o > 0; o >>= 1) {
                unsigned long long oth = __shfl_xor(km, o);
                km = (oth > km) ? oth : km;
            }
            int sidx = 63 - (int)(km & 0xffffffffull);
            float esel = __shfl(e, sidx);
            if (lane == 0) {
                selpos_s[b][ts] = sidx;
                nscore_s[b][ts] = logf(esel / den + 1e-20f);
            }
            if (lane == sidx) mlc = -INFINITY;
        }
    }
    __syncthreads();
    // ---- phase 2: beam select on wave 0 (candidate c lives in lane c) ----
    if (wave == 0) {
        const int C = B * topk;
        float ac = 0.f, bc = 0.f;
        if (lane < C) {
            const int pb = lane / topk, ptt = lane - pb * topk;
            ac = accu[n*BEAM + pb] + nscore_s[pb][ptt];
            const float nb = done * ((ptt == 0) ? 1.f : 0.f) + (1.f - done);
            bc = bmask[n*BEAM + pb] * nb;
        }
        bool used = false;
        for (int k = 0; k < BEAM; ++k) {
            int bestc;
            if (do_bsel) {
                const float v = (lane < C && !used)
                                ? ((bc > 0.f) ? ac : -1e9f) : -INFINITY;
                unsigned fb = __float_as_uint(v);
                unsigned ok = (fb & 0x80000000u) ? ~fb : (fb | 0x80000000u);
                unsigned long long key =
                    ((unsigned long long)ok << 32) | (unsigned)(63 - lane);
                unsigned long long km = key;
                #pragma unroll
                for (int o = 32; o > 0; o >>= 1) {
                    unsigned long long oth = __shfl_xor(km, o);
                    km = (oth > km) ? oth : km;
                }
                bestc = 63 - (int)(km & 0xffffffffull);
            } else bestc = k;
            if (lane == bestc) used = true;
            const float av  = __shfl(ac, bestc);
            const float bv2 = __shfl(bc, bestc);
            const int pp = bestc / topk, ss = selpos_s[pp][bestc - pp * topk];
            if (lane == 0) {
                parent[n*BEAM + k] = pp;
                posb[n*BEAM + k]   = ss;
                par_s[k] = pp; pos_s[k] = ss;
                accu_out[n*BEAM + k] = av;
                bm_out[n*BEAM + k]   = bv2;
            }
        }
    }
    __syncthreads();
    // ---- phase 3: l/r arena row ids (threads 0..BEAM-1) ----
    if (t < BEAM) {
        const int base = (n*BAo + par_s[t]) * STo + pos_s[t];
        lrid[n*BEAM + t] = idxold[base];
        rrid[n*BEAM + t] = idxold[base + 1];
    }
    // ---- phase 4: wave k copies beam k's compacted score row ----
    if (dow && wave < BEAM) {
        const int k = wave;
        const int p = par_s[k], s = pos_s[k];
        if (lane < Snew) {
            float v = 0.f;
            if (lane < s - 1)      v = w[(n*BEAM + p)*S0 + lane];
            else if (lane > s)     v = w[(n*BEAM + p)*S0 + lane + 1];
            wnew[(n*BEAM + k)*S0 + lane] = v;
        }
    }
}

// ======== compose: sum 4 partials + gate softmax + mix + LN -> arena ========
__global__ __launch_bounds__(256) void k_compose(
    const float* __restrict__ P,
    const _Float16* __restrict__ cha_r, const _Float16* __restrict__ cla_r,
    const int* __restrict__ lrid, const int* __restrict__ rrid,
    const int* __restrict__ parent, const int* __restrict__ posb,
    const int* __restrict__ idxold, int BAo, int STo,
    const float* __restrict__ maskg, int iiter, int Spnew,
    const float* __restrict__ gp, const float* __restrict__ bp,
    _Float16* __restrict__ cha_w, _Float16* __restrict__ cla_w, int newbase,
    int* __restrict__ idxnew, int finalflag, float* __restrict__ nvout)
{
    __shared__ float sb[8];
    const int nk = blockIdx.x, t = threadIdx.x;
    const int n = nk / BEAM;
    size_t lbase, rbase;
    if (finalflag) {
        lbase = (size_t)idxold[nk*31 + 0] * 512;
        rbase = (size_t)idxold[nk*31 + 1] * 512;
    } else {
        lbase = (size_t)lrid[nk] * 512;
        rbase = (size_t)rrid[nk] * 512;
    }
    const float* c = P + (size_t)nk * CHID;
    float o[2];
    #pragma unroll
    for (int e = 0; e < 2; ++e) {
        const int d = t + 256*e;
        const float lv = recon(cha_r[lbase + d], cla_r[lbase + d]);
        const float rv = recon(cha_r[rbase + d], cla_r[rbase + d]);
        float c0 = ((c[d]        + c[MN2 + d])        + c[2*MN2 + d])        + c[3*MN2 + d];
        float c1 = ((c[DD + d]   + c[MN2 + DD + d])   + c[2*MN2 + DD + d])   + c[3*MN2 + DD + d];
        float c2 = ((c[2*DD + d] + c[MN2 + 2*DD + d]) + c[2*MN2 + 2*DD + d]) + c[3*MN2 + 2*DD + d];
        float c3 = ((c[3*DD + d] + c[MN2 + 3*DD + d]) + c[2*MN2 + 3*DD + d]) + c[3*MN2 + 3*DD + d];
        float m = fmaxf(c0, fmaxf(c1, c2));
        float e0 = expf(c0 - m), e1 = expf(c1 - m), e2 = expf(c2 - m);
        float inv = 1.f / (e0 + e1 + e2);
        o[e] = (e0*lv + e1*rv + e2*c3) * inv;
    }
    float s1 = block_reduce_sum(o[0] + o[1], sb);
    float s2 = block_reduce_sum(o[0]*o[0] + o[1]*o[1], sb);
    float mu = s1 * (1.f/512.f);
    float rstd = rsqrtf(s2 * (1.f/512.f) - mu*mu + 1e-5f);
    if (finalflag) {
        #pragma unroll
        for (int e = 0; e < 2; ++e) {
            const int d = t + 256*e;
            nvout[(size_t)nk*DD + d] = (o[e] - mu) * rstd * gp[d] + bp[d];
        }
        return;
    }
    const int arow = newbase + nk;
    #pragma unroll
    for (int e = 0; e < 2; ++e) {
        const int d = t + 256*e;
        float v = (o[e] - mu) * rstd * gp[d] + bp[d];
        _Float16 h = hi16(v);
        cha_w[(size_t)arow*512 + d] = h;
        cla_w[(size_t)arow*512 + d] = lo16(v, h);
    }
    if (t < Spnew) {
        const float done = maskg[n*S0 + iiter + 1];
        const int p = parent[nk], s = posb[nk];
        const int src = (n*BAo + p) * STo;
        int val;
        if (done > 0.5f)
            val = (t < s) ? idxold[src + t] : (t == s ? arow : idxold[src + t + 1]);
        else
            val = idxold[src + t];
        idxnew[nk*31 + t] = val;
    }
}

// ============ final beam softmax mix ============
__global__ __launch_bounds__(256) void k_final(
    const float* __restrict__ nv,
    const _Float16* __restrict__ cha, const _Float16* __restrict__ cla,
    const int* __restrict__ idxt, const float* __restrict__ maskg,
    const float* __restrict__ accu, const float* __restrict__ bmv,
    float* __restrict__ out)
{
    const int n = blockIdx.x, t = threadIdx.x;
    const float done = maskg[n*S0 + 31];
    float sc[BEAM];
    #pragma unroll
    for (int k = 0; k < BEAM; ++k) {
        float m = bmv[n*BEAM + k];
        sc[k] = m * accu[n*BEAM + k] + (1.f - m) * (-999999.f);
    }
    float mx = sc[0];
    #pragma unroll
    for (int k = 1; k < BEAM; ++k) mx = fmaxf(mx, sc[k]);
    float e[BEAM], den = 0.f;
    #pragma unroll
    for (int k = 0; k < BEAM; ++k) { e[k] = expf(sc[k] - mx); den += e[k]; }
    const float inv = 1.f / den;
    #pragma unroll
    for (int i2 = 0; i2 < 2; ++i2) {
        const int d = t + 256*i2;
        float s = 0.f;
        #pragma unroll
        for (int k = 0; k < BEAM; ++k) {
            const int nk = n*BEAM + k;
            const size_t ob = (size_t)idxt[nk*31] * 512;
            const float nvv  = nv[(size_t)nk*DD + d];
            const float oldv = recon(cha[ob + d], cla[ob + d]);
            s += e[k]*inv * (done*nvv + (1.f - done)*oldv);
        }
        out[(size_t)n*DD + d] = s;
    }
}

extern "C" void kernel_launch(void* const* d_in, const int* in_sizes, int n_in,
                              void* d_out, int out_size, void* d_ws, size_t ws_size,
                              hipStream_t stream) {
    (void)in_sizes; (void)n_in; (void)out_size; (void)ws_size;
    const float* x    = (const float*)d_in[0];
    const float* mask = (const float*)d_in[1];
    const float* Wi   = (const float*)d_in[2];
    const float* bi   = (const float*)d_in[3];
    const float* g1   = (const float*)d_in[4];
    const float* b1   = (const float*)d_in[5];
    const float* Wd1  = (const float*)d_in[6];
    const float* bd1  = (const float*)d_in[7];
    const float* Wd2  = (const float*)d_in[8];
    const float* bd2  = (const float*)d_in[9];
    const float* Wc1  = (const float*)d_in[10];
    const float* bc1  = (const float*)d_in[11];
    const float* Wc2  = (const float*)d_in[12];
    const float* bc2  = (const float*)d_in[13];
    const float* g2   = (const float*)d_in[14];
    const float* b2   = (const float*)d_in[15];
    float* out = (float*)d_out;

    // ---- workspace carve-up (bytes), ~185 MB ----
    char* p = (char*)d_ws;
    _Float16* cha = (_Float16*)p;        p += (size_t)AR_TOT*512*2;
    _Float16* cla = (_Float16*)p;        p += (size_t)AR_TOT*512*2;
    _Float16* Wc1th = (_Float16*)p;      p += (size_t)CHID*1024*2;
    _Float16* Wc1tl = (_Float16*)p;      p += (size_t)CHID*1024*2;
    _Float16* Wc2th = (_Float16*)p;      p += (size_t)CHID*CHID*2;
    _Float16* Wc2tl = (_Float16*)p;      p += (size_t)CHID*CHID*2;
    _Float16* Wd1th = (_Float16*)p;      p += (size_t)512*1024*2;
    _Float16* Wd1tl = (_Float16*)p;      p += (size_t)512*1024*2;
    _Float16* Wih = (_Float16*)p;        p += (size_t)WDIM*DD*2;
    _Float16* Wil = (_Float16*)p;        p += (size_t)WDIM*DD*2;
    _Float16* Hh  = (_Float16*)p;        p += (size_t)NB*CHID*2;
    _Float16* Hl  = (_Float16*)p;        p += (size_t)NB*CHID*2;
    float* Pb   = (float*)p;             p += MN2*4*4;                // 4 slices
    float* nvb  = (float*)p;             p += (size_t)NB*DD*4;
    float* wA   = (float*)p;             p += (size_t)NB*S0*4;
    float* wB   = (float*)p;             p += (size_t)NB*S0*4;
    float* accA = (float*)p;             p += NB*4;
    float* accB = (float*)p;             p += NB*4;
    float* bmA  = (float*)p;             p += NB*4;
    float* bmB  = (float*)p;             p += NB*4;
    int* parent = (int*)p;               p += NB*4;
    int* posb   = (int*)p;               p += NB*4;
    int* lrid   = (int*)p;               p += NB*4;
    int* rrid   = (int*)p;               p += NB*4;
    int* idx0   = (int*)p;               p += AR_INIT*4;
    int* idxA   = (int*)p;               p += NB*31*4;
    int* idxB   = (int*)p;               p += NB*31*4;
    // init-only aliases inside Pb
    _Float16* xh = (_Float16*)Pb;
    _Float16* xl = (_Float16*)((char*)Pb + (size_t)AR_INIT*512*2);
    float* ybuf  = (float*)((char*)Pb + (size_t)AR_INIT*512*4);

    // ---- prep ----
    k_tsplit<<<dim3(CHID/32, 1024/32), 256, 0, stream>>>(Wc1, Wc1th, Wc1tl, 1024, CHID);
    k_tsplit<<<dim3(CHID/32, CHID/32), 256, 0, stream>>>(Wc2, Wc2th, Wc2tl, CHID, CHID);
    k_tsplit<<<dim3(512/32, 1024/32), 256, 0, stream>>>(Wd1, Wd1th, Wd1tl, 1024, 512);
    k_tsplit<<<dim3(DD/32, WDIM/32), 256, 0, stream>>>(Wi, Wih, Wil, WDIM, DD);
    k_init_state<<<(NB*S0 + 255)/256, 256, 0, stream>>>(accA, bmA, idx0, wA);

    // ---- init: arena rows 0..8191 = LN(x@Wi+bi) ----
    k_xsplit<<<(AR_INIT*WDIM)/1024, 256, 0, stream>>>(x, xh, xl);
    k_gemm<0><<<dim3(DD/128, AR_INIT/128, 1), 256, 0, stream>>>(
        xh, xl, Wih, Wil, bi, ybuf, AR_INIT, DD, WDIM, WDIM);
    k_ln_init<<<AR_INIT, 256, 0, stream>>>(ybuf, g1, b1, cha, cla);
    k_wscore<0><<<dim3(NN*31/64, 8), 256, 0, stream>>>(
        cha, cla, nullptr, nullptr, Wd1th, Wd1tl, bd1, Wd2, bd2, wA, 31);

    const int* idxcur = idx0;
    int* idxnxt = idxA;
    int BAo = 1, STo = 32;
    float *wcur = wA, *wnxt = wB;
    float *acur = accA, *anxt = accB, *bcur = bmA, *bnxt = bmB;
    for (int i = 0; i < 30; ++i) {
        const int B  = (i == 0) ? 1 : BEAM;
        const int S  = 31 - i;
        const int tk = (S < BEAM) ? S : BEAM;
        const int dob = (B*tk > BEAM) ? 1 : 0;
        const int newbase = AR_INIT + i*NB;
        k_topk<<<NN, 320, 0, stream>>>(wcur, acur, bcur, mask, i, B, S, tk, dob,
                                       idxcur, BAo, STo, parent, posb, lrid, rrid,
                                       anxt, bnxt, wnxt, S - 1, (i < 29) ? 1 : 0);
        k_gemm1<1><<<dim3(CHID/64, NB/128), 256, 0, stream>>>(
            cha, cla, Wc1th, Wc1tl, bc1, Hh, Hl, lrid, rrid, nullptr, CHID);
        k_gemm<0><<<dim3(CHID/128, NB/128, 4), 256, 0, stream>>>(
            Hh, Hl, Wc2th, Wc2tl, bc2, Pb, NB, CHID, CHID, 512);
        k_compose<<<NB, 256, 0, stream>>>(Pb, cha, cla, lrid, rrid, parent, posb,
                                          idxcur, BAo, STo, mask, i, 31 - i,
                                          g2, b2, cha, cla, newbase, idxnxt,
                                          0, nullptr);
        if (i < 29)
            k_wscore<1><<<dim3(NB*2/64, 8), 256, 0, stream>>>(
                cha, cla, posb, idxnxt, Wd1th, Wd1tl, bd1, Wd2, bd2, wnxt, S - 1);
        idxcur = idxnxt;
        idxnxt = (idxnxt == idxA) ? idxB : idxA;
        BAo = BEAM; STo = 31;
        float* tp;
        tp = wcur; wcur = wnxt; wnxt = tp;
        tp = acur; acur = anxt; anxt = tp;
        tp = bcur; bcur = bnxt; bnxt = tp;
    }
    // final compose: l,r = table positions 0,1
    k_gemm1<2><<<dim3(CHID/64, NB/128), 256, 0, stream>>>(
        cha, cla, Wc1th, Wc1tl, bc1, Hh, Hl, nullptr, nullptr, idxcur, CHID);
    k_gemm<0><<<dim3(CHID/128, NB/128, 4), 256, 0, stream>>>(
        Hh, Hl, Wc2th, Wc2tl, bc2, Pb, NB, CHID, CHID, 512);
    k_compose<<<NB, 256, 0, stream>>>(Pb, cha, cla, nullptr, nullptr, parent, posb,
                                      idxcur, BEAM, 31, mask, 30, 0,
                                      g2, b2, nullptr, nullptr, 0,
                                      nullptr, 1, nvb);
    k_final<<<NN, 256, 0, stream>>>(nvb, cha, cla, idxcur, mask, acur, bcur, out);
}

// Round 6
// 3505.737 us; speedup vs baseline: 1.1874x; 1.1874x over previous
//
#include <hip/hip_runtime.h>
#include <math.h>

// EBT_GRC beam-search forward, round 16 (= round-15 occupancy attack with
// relaxed launch_bounds: two consecutive "container failed twice" runs with
// the (256,3)/(256,4) build; the hard min-waves regalloc constraint is the
// only unauditable novelty vs the known-good r13 build, so drop to (256,1)
// and let LDS sizing drive residency: 48KB dbuf -> 3 blk/CU naturally,
// ~100 VGPR kernel).
// r14 post-mortem: depth-3 counted-vmcnt prefetch = null -> latency-bound
// with OccupancyPercent 8.5% (~0.7 waves/SIMD). Fix = more resident waves:
//  - k_gemm: BM 128->64 (wave tile 32x64), 24KB/stage dbuf=48KB -> 3 blk/CU.
//  - split-K z 4->2: WRITE 41->20.5MB, compose partial reads halved.
//  - k_gemm1: 64x64 tiles, 640 blocks, 32KB dbuf.
// N=256, S=32, D=512, CH=2048, BEAM=5. WS ~185 MB.

#define NN   256
#define S0   32
#define WDIM 512
#define DD   512
#define CHID 2048
#define BEAM 5
#define NB   (NN*BEAM)   // 1280
#define RSCALE 2048.0f
#define RINV  (1.0f/2048.0f)
#define AR_INIT 8192
#define AR_TOT  (AR_INIT + 30*NB)    // 46592 rows
#define MN2 ((size_t)NB*CHID)        // partial-buffer slice stride
#define ZSPLIT 2

typedef __attribute__((ext_vector_type(8))) _Float16 f16x8;
typedef __attribute__((ext_vector_type(4))) float f32x4;

__device__ __forceinline__ float gelu_f(float x) {
    return 0.5f * x * (1.0f + erff(x * 0.7071067811865475f));
}
__device__ __forceinline__ _Float16 hi16(float v) { return (_Float16)v; }
__device__ __forceinline__ _Float16 lo16(float v, _Float16 h) {
    return (_Float16)((v - (float)h) * RSCALE);
}
__device__ __forceinline__ float recon(_Float16 h, _Float16 l) {
    return (float)h + RINV * (float)l;
}

__device__ __forceinline__ void gload_lds16(const void* g, void* l) {
    __builtin_amdgcn_global_load_lds(
        (const __attribute__((address_space(1))) unsigned*)g,
        (__attribute__((address_space(3))) unsigned*)l, 16, 0, 0);
}

__device__ __forceinline__ float block_reduce_sum(float v, float* sb) {
    #pragma unroll
    for (int o = 32; o > 0; o >>= 1) v += __shfl_down(v, o);
    const int lane = threadIdx.x & 63, wid = threadIdx.x >> 6;
    __syncthreads();
    if (lane == 0) sb[wid] = v;
    __syncthreads();
    return sb[0] + sb[1] + sb[2] + sb[3];
}

// ===== fp16x2 split MFMA GEMM, 64x128 tile, split-K, LDS dbuf =====
template<int AIDX>
__global__ __launch_bounds__(256, 1) void k_gemm(
    const _Float16* __restrict__ Ah, const _Float16* __restrict__ Al,
    const _Float16* __restrict__ Bh, const _Float16* __restrict__ Bl,
    const float* __restrict__ bias, float* __restrict__ Cf,
    int M, int N, int Ktot, int Kchunk)
{
    // per stage: Ah[0,2048) Al[2048,4096) Bh[4096,8192) Bl[8192,12288) halves
    __shared__ __align__(16) _Float16 lds[2][12288];   // 48 KB
    const int t = threadIdx.x, wave = t >> 6, lane = t & 63;
    const int bm = blockIdx.y * 64, bn = blockIdx.x * 128;
    const int koff = blockIdx.z * Kchunk;
    const int wm = (wave >> 1) * 32, wn = (wave & 1) * 64;   // wave tile 32x64
    const int rsub = lane >> 2, seg = lane & 3;
    const int fm = lane & 15, quad = lane >> 4, fko = quad * 8;

    f32x4 acc0[2][4], acc1[2][4];
    #pragma unroll
    for (int i = 0; i < 2; ++i)
        #pragma unroll
        for (int j = 0; j < 4; ++j) {
            acc0[i][j] = (f32x4){0.f, 0.f, 0.f, 0.f};
            acc1[i][j] = (f32x4){0.f, 0.f, 0.f, 0.f};
        }

    const int iters = Kchunk >> 5;
    // 6 global_load_lds per wave per stage: A panel `wave` (h,l), B panels 2w,2w+1
    #define STAGE_G(IT, BUF) {                                                 \
        const int k = koff + (IT)*32;                                          \
        _Float16* Lb = &lds[BUF][0];                                           \
        const size_t aoff = (size_t)(bm + wave*16 + rsub) * Ktot + k + seg*8;  \
        gload_lds16(Ah + aoff, Lb + wave*512);                                 \
        gload_lds16(Al + aoff, Lb + 2048 + wave*512);                          \
        _Pragma("unroll")                                                      \
        for (int j = 0; j < 2; ++j) {                                          \
            const int q = wave * 2 + j;                                        \
            const size_t boff = (size_t)(bn + q*16 + rsub) * Ktot + k + seg*8; \
            gload_lds16(Bh + boff, Lb + 4096 + q*512);                         \
            gload_lds16(Bl + boff, Lb + 8192 + q*512);                         \
        } }

    STAGE_G(0, 0);
    for (int it = 0; it < iters; ++it) {
        __syncthreads();
        if (it + 1 < iters) STAGE_G(it + 1, (it + 1) & 1);
        const _Float16* L = &lds[it & 1][0];
        f16x8 ah[2], al[2];
        #pragma unroll
        for (int i = 0; i < 2; ++i) {
            const int ar = wm + i*16 + fm;
            ah[i] = *(const f16x8*)&L[ar*32 + fko];
            al[i] = *(const f16x8*)&L[2048 + ar*32 + fko];
        }
        #pragma unroll
        for (int j = 0; j < 4; ++j) {
            const int br = wn + j*16 + fm;
            f16x8 bh = *(const f16x8*)&L[4096 + br*32 + fko];
            f16x8 bl = *(const f16x8*)&L[8192 + br*32 + fko];
            #pragma unroll
            for (int i = 0; i < 2; ++i) {
                acc0[i][j] = __builtin_amdgcn_mfma_f32_16x16x32_f16(ah[i], bh, acc0[i][j], 0, 0, 0);
                acc1[i][j] = __builtin_amdgcn_mfma_f32_16x16x32_f16(ah[i], bl, acc1[i][j], 0, 0, 0);
                acc1[i][j] = __builtin_amdgcn_mfma_f32_16x16x32_f16(al[i], bh, acc1[i][j], 0, 0, 0);
            }
        }
    }
    float* dst = Cf + (size_t)blockIdx.z * M * N;
    #pragma unroll
    for (int i = 0; i < 2; ++i)
        #pragma unroll
        for (int j = 0; j < 4; ++j) {
            const int col = bn + wn + j*16 + fm;
            const float bv = (blockIdx.z == 0) ? bias[col] : 0.f;
            #pragma unroll
            for (int r = 0; r < 4; ++r) {
                const int row = bm + wm + i*16 + quad*4 + r;
                dst[(size_t)row * N + col] = acc0[i][j][r] + acc1[i][j][r] * RINV + bv;
            }
        }
    #undef STAGE_G
}

// ==== GEMM1 fused: H = gelu(cat@Wc1+bc1) -> fp16 h/l, 64x64 tiles, dbuf ====
template<int AIDX>
__global__ __launch_bounds__(256, 1) void k_gemm1(
    const _Float16* __restrict__ Ah, const _Float16* __restrict__ Al,
    const _Float16* __restrict__ Bh, const _Float16* __restrict__ Bl,
    const float* __restrict__ bias,
    _Float16* __restrict__ Oh, _Float16* __restrict__ Ol,
    const int* __restrict__ lrid, const int* __restrict__ rrid,
    const int* __restrict__ idxt, int N)
{
    // per stage: Ah[0,2048) Al[2048,4096) Bh[4096,6144) Bl[6144,8192) halves
    __shared__ __align__(16) _Float16 lds[2][8192];   // 32 KB
    const int t = threadIdx.x, wave = t >> 6, lane = t & 63;
    const int bm = blockIdx.y * 64, bn = blockIdx.x * 64;
    const int rsub = lane >> 2, seg = lane & 3;
    const int fm = lane & 15, quad = lane >> 4, fko = quad * 8;
    const int wr = wave >> 1, wc = wave & 1;   // wave tile 32x32

    size_t lb, rb;
    {
        const int rowm = bm + wave*16 + rsub;
        if (AIDX == 1) {
            lb = (size_t)lrid[rowm] * 512;
            rb = (size_t)rrid[rowm] * 512;
        } else {
            lb = (size_t)idxt[rowm*31 + 0] * 512;
            rb = (size_t)idxt[rowm*31 + 1] * 512;
        }
    }
    const size_t bbase = (size_t)(bn + wave*16 + rsub) * 1024;

    f32x4 acc0[2][2], acc1[2][2];
    #pragma unroll
    for (int i = 0; i < 2; ++i)
        #pragma unroll
        for (int j = 0; j < 2; ++j) {
            acc0[i][j] = (f32x4){0.f, 0.f, 0.f, 0.f};
            acc1[i][j] = (f32x4){0.f, 0.f, 0.f, 0.f};
        }

    // 4 global_load_lds per wave per stage
    #define STAGE_G1(IT, BUF) {                                                 \
        const int k0 = (IT)*32;                                                 \
        _Float16* Lb = &lds[BUF][0];                                            \
        const size_t aoff = (k0 < 512 ? lb + k0 : rb + (k0-512)) + seg*8;       \
        gload_lds16(Ah + aoff, Lb + wave*512);                                  \
        gload_lds16(Al + aoff, Lb + 2048 + wave*512);                           \
        gload_lds16(Bh + bbase + k0 + seg*8, Lb + 4096 + wave*512);             \
        gload_lds16(Bl + bbase + k0 + seg*8, Lb + 6144 + wave*512); }

    STAGE_G1(0, 0);
    for (int it = 0; it < 32; ++it) {
        __syncthreads();
        if (it + 1 < 32) STAGE_G1(it + 1, (it + 1) & 1);
        const _Float16* L = &lds[it & 1][0];
        f16x8 ah[2], al[2];
        #pragma unroll
        for (int i = 0; i < 2; ++i) {
            const int ar = wr*32 + i*16 + fm;
            ah[i] = *(const f16x8*)&L[ar*32 + fko];
            al[i] = *(const f16x8*)&L[2048 + ar*32 + fko];
        }
        #pragma unroll
        for (int j = 0; j < 2; ++j) {
            const int br = wc*32 + j*16 + fm;
            f16x8 bh = *(const f16x8*)&L[4096 + br*32 + fko];
            f16x8 bl = *(const f16x8*)&L[6144 + br*32 + fko];
            #pragma unroll
            for (int i = 0; i < 2; ++i) {
                acc0[i][j] = __builtin_amdgcn_mfma_f32_16x16x32_f16(ah[i], bh, acc0[i][j], 0, 0, 0);
                acc1[i][j] = __builtin_amdgcn_mfma_f32_16x16x32_f16(ah[i], bl, acc1[i][j], 0, 0, 0);
                acc1[i][j] = __builtin_amdgcn_mfma_f32_16x16x32_f16(al[i], bh, acc1[i][j], 0, 0, 0);
            }
        }
    }
    #pragma unroll
    for (int i = 0; i < 2; ++i)
        #pragma unroll
        for (int j = 0; j < 2; ++j) {
            const int col = bn + wc*32 + j*16 + fm;
            const float bv = bias[col];
            #pragma unroll
            for (int r = 0; r < 4; ++r) {
                const int row = bm + wr*32 + i*16 + quad*4 + r;
                float v = gelu_f(acc0[i][j][r] + acc1[i][j][r] * RINV + bv);
                _Float16 h = hi16(v);
                Oh[(size_t)row * N + col] = h;
                Ol[(size_t)row * N + col] = lo16(v, h);
            }
        }
    #undef STAGE_G1
}

// ====== fused score (64x64 tiles, dbuf): w += gelu(cat@Wd1+bd1)@Wd2 ======
template<int MODE>
__global__ __launch_bounds__(256, 2) void k_wscore(
    const _Float16* __restrict__ ch, const _Float16* __restrict__ cl,
    const int* __restrict__ posb, const int* __restrict__ idxt,
    const _Float16* __restrict__ Bh, const _Float16* __restrict__ Bl,
    const float* __restrict__ bd1, const float* __restrict__ u512,
    const float* __restrict__ bd2, float* __restrict__ w, int Spairs)
{
    __shared__ __align__(16) _Float16 lds[2][8192];   // 32 KB
    const int t = threadIdx.x, wave = t >> 6, lane = t & 63;
    const int bm = blockIdx.x * 64, ncol0 = blockIdx.y * 64;
    const int rsub = lane >> 2, seg = lane & 3;
    const int fm = lane & 15, quad = lane >> 4, fko = quad * 8;

    size_t lb, rb;
    {
        const int rowm = bm + wave*16 + rsub;
        int lrow, rrow;
        if (MODE == 0) {
            const int n = rowm / 31, s = rowm - n * 31;
            lrow = n*32 + s; rrow = lrow + 1;
        } else {
            const int nk = rowm >> 1, slot = rowm & 1;
            const int s = posb[nk];
            int jw = s - 1 + slot;
            int jc = jw < 0 ? 0 : (jw > Spairs - 1 ? Spairs - 1 : jw);
            lrow = idxt[nk*31 + jc]; rrow = idxt[nk*31 + jc + 1];
        }
        lb = (size_t)lrow * 512; rb = (size_t)rrow * 512;
    }
    const size_t bbase = (size_t)(ncol0 + wave*16 + rsub) * 1024;

    f32x4 acc0[4], acc1[4];
    #pragma unroll
    for (int j = 0; j < 4; ++j) {
        acc0[j] = (f32x4){0.f, 0.f, 0.f, 0.f};
        acc1[j] = (f32x4){0.f, 0.f, 0.f, 0.f};
    }
    #define STAGE_WS(IT, BUF) {                                                \
        const int k0 = (IT)*32;                                                \
        _Float16* Lb = &lds[BUF][0];                                           \
        const size_t aoff = (k0 < 512 ? lb + k0 : rb + (k0-512)) + seg*8;      \
        gload_lds16(ch + aoff, Lb + 0*2048 + wave*512);                        \
        gload_lds16(cl + aoff, Lb + 1*2048 + wave*512);                        \
        gload_lds16(Bh + bbase + k0 + seg*8, Lb + 2*2048 + wave*512);          \
        gload_lds16(Bl + bbase + k0 + seg*8, Lb + 3*2048 + wave*512); }

    STAGE_WS(0, 0);
    for (int it = 0; it < 32; ++it) {
        __syncthreads();
        if (it + 1 < 32) STAGE_WS(it + 1, (it + 1) & 1);
        const _Float16* L = &lds[it & 1][0];
        const int ar = wave*16 + fm;
        f16x8 ah = *(const f16x8*)&L[0*2048 + ar*32 + fko];
        f16x8 al = *(const f16x8*)&L[1*2048 + ar*32 + fko];
        #pragma unroll
        for (int j = 0; j < 4; ++j) {
            const int br = j*16 + fm;
            f16x8 bh = *(const f16x8*)&L[2*2048 + br*32 + fko];
            f16x8 bl = *(const f16x8*)&L[3*2048 + br*32 + fko];
            acc0[j] = __builtin_amdgcn_mfma_f32_16x16x32_f16(ah, bh, acc0[j], 0, 0, 0);
            acc1[j] = __builtin_amdgcn_mfma_f32_16x16x32_f16(ah, bl, acc1[j], 0, 0, 0);
            acc1[j] = __builtin_amdgcn_mfma_f32_16x16x32_f16(al, bh, acc1[j], 0, 0, 0);
        }
    }
    float part[4] = {0.f, 0.f, 0.f, 0.f};
    #pragma unroll
    for (int j = 0; j < 4; ++j) {
        const int col = ncol0 + j*16 + fm;
        const float bv = bd1[col], uv = u512[col];
        #pragma unroll
        for (int r = 0; r < 4; ++r) {
            float v = acc0[j][r] + acc1[j][r] * RINV + bv;
            part[r] += gelu_f(v) * uv;
        }
    }
    #pragma unroll
    for (int r = 0; r < 4; ++r) {
        float s = part[r];
        s += __shfl_xor(s, 1); s += __shfl_xor(s, 2);
        s += __shfl_xor(s, 4); s += __shfl_xor(s, 8);
        part[r] = s;
    }
    if (fm == 0) {
        const float bd2v = (blockIdx.y == 0) ? bd2[0] : 0.f;
        #pragma unroll
        for (int r = 0; r < 4; ++r) {
            const int rowm = bm + wave*16 + quad*4 + r;
            int wi = -1;
            if (MODE == 0) {
                const int n = rowm / 31, s = rowm - n * 31;
                wi = n * BEAM * S0 + s;
            } else {
                const int nk = rowm >> 1, slot = rowm & 1;
                const int jw = posb[nk] - 1 + slot;
                if (jw >= 0 && jw < Spairs) wi = nk * S0 + jw;
            }
            if (wi >= 0) atomicAdd(&w[wi], part[r] + bd2v);
        }
    }
    #undef STAGE_WS
}

// ============ weight transpose + fp16 split ============
__global__ __launch_bounds__(256) void k_tsplit(
    const float* __restrict__ in, _Float16* __restrict__ oh,
    _Float16* __restrict__ ol, int K, int N)
{
    __shared__ float tile[32][33];
    const int bx = blockIdx.x * 32, by = blockIdx.y * 32;
    const int t = threadIdx.x, r = t >> 5, c = t & 31;
    #pragma unroll
    for (int p = 0; p < 4; ++p)
        tile[r + p*8][c] = in[(size_t)(by + r + p*8) * N + bx + c];
    __syncthreads();
    #pragma unroll
    for (int p = 0; p < 4; ++p) {
        const int nl = r + p*8;
        float v = tile[c][nl];
        _Float16 h = hi16(v);
        oh[(size_t)(bx + nl) * K + by + c] = h;
        ol[(size_t)(bx + nl) * K + by + c] = lo16(v, h);
    }
}

// ============ elementwise fp16 split (x rows, init only) ============
__global__ __launch_bounds__(256) void k_xsplit(
    const float* __restrict__ in, _Float16* __restrict__ oh,
    _Float16* __restrict__ ol)
{
    const size_t i = ((size_t)blockIdx.x * 256 + threadIdx.x) * 4;
    float4 v = *(const float4*)(in + i);
    _Float16 h0 = hi16(v.x), h1 = hi16(v.y), h2 = hi16(v.z), h3 = hi16(v.w);
    typedef __attribute__((ext_vector_type(4))) _Float16 f16x4v;
    f16x4v h = {h0, h1, h2, h3};
    f16x4v l = {lo16(v.x,h0), lo16(v.y,h1), lo16(v.z,h2), lo16(v.w,h3)};
    *(f16x4v*)(oh + i) = h;
    *(f16x4v*)(ol + i) = l;
}

// ============ init layernorm -> split arena rows ============
__global__ __launch_bounds__(256) void k_ln_init(
    const float* __restrict__ y, const float* __restrict__ g,
    const float* __restrict__ b, _Float16* __restrict__ cha,
    _Float16* __restrict__ cla)
{
    const int row = blockIdx.x;
    const float* yr = y + (size_t)row * DD;
    const int t = threadIdx.x;
    float v0 = yr[t], v1 = yr[t + 256];
    __shared__ float sb[8];
    float s1 = block_reduce_sum(v0 + v1, sb);
    float s2 = block_reduce_sum(v0*v0 + v1*v1, sb);
    float mu = s1 * (1.f/512.f);
    float rstd = rsqrtf(s2 * (1.f/512.f) - mu*mu + 1e-5f);
    float a0 = (v0 - mu) * rstd * g[t]       + b[t];
    float a1 = (v1 - mu) * rstd * g[t + 256] + b[t + 256];
    _Float16 h0 = hi16(a0), h1 = hi16(a1);
    cha[(size_t)row*DD + t]       = h0;
    cla[(size_t)row*DD + t]       = lo16(a0, h0);
    cha[(size_t)row*DD + t + 256] = h1;
    cla[(size_t)row*DD + t + 256] = lo16(a1, h1);
}

__global__ void k_init_state(float* accu, float* bm, int* idx0, float* wz) {
    int i = blockIdx.x * blockDim.x + threadIdx.x;
    if (i < NB*S0) wz[i] = 0.f;
    if (i < AR_INIT) idx0[i] = i;
    if (i < NB) { accu[i] = 0.f; bm[i] = 1.f; }
}

// ====== top-k (5 waves: wave b = beam b) + beam select + l/r row ids ======
__global__ __launch_bounds__(320) void k_topk(
    const float* __restrict__ w, const float* __restrict__ accu,
    const float* __restrict__ bmask, const float* __restrict__ maskg,
    int iiter, int B, int S, int topk, int do_bsel,
    const int* __restrict__ idxold, int BAo, int STo,
    int* __restrict__ parent, int* __restrict__ posb,
    int* __restrict__ lrid, int* __restrict__ rrid,
    float* __restrict__ accu_out, float* __restrict__ bm_out,
    float* __restrict__ wnew, int Snew, int dow)
{
    const int n = blockIdx.x, t = threadIdx.x;
    const int wave = t >> 6, lane = t & 63;
    __shared__ int   selpos_s[BEAM][BEAM];
    __shared__ float nscore_s[BEAM][BEAM];
    __shared__ int   par_s[BEAM], pos_s[BEAM];
    const float* mrow = maskg + n*S0 + (iiter + 1);
    const float mk   = (lane < S) ? mrow[lane] : 0.f;
    const float done = 1.f - mrow[0];
    // ---- phase 1: wave b computes beam b's masked softmax + top-k ----
    if (wave < B) {
        const int b = wave;
        float ml;
        if (lane < S) {
            float wv = w[(n*BEAM + b)*S0 + lane];
            ml = (mk > 0.f) ? wv : -1e9f;
        } else ml = -INFINITY;
        float mx = ml;
        #pragma unroll
        for (int o = 32; o > 0; o >>= 1) mx = fmaxf(mx, __shfl_xor(mx, o));
        float e = (lane < S) ? expf(ml - mx) * mk : 0.f;
        float es = e;
        #pragma unroll
        for (int o = 32; o > 0; o >>= 1) es += __shfl_xor(es, o);
        const float den = es + 1e-20f;
        float mlc = ml;
        for (int ts = 0; ts < topk; ++ts) {
            unsigned int fb = __float_as_uint(mlc);
            unsigned int ok = (fb & 0x80000000u) ? ~fb : (fb | 0x80000000u);
            unsigned long long key =
                ((unsigned long long)ok << 32) | (unsigned int)(63 - lane);
            if (lane >= S) key = 0ull;
            unsigned long long km = key;
            #pragma unroll
            for (int o = 32; o > 0; o >>= 1) {
                unsigned long long oth = __shfl_xor(km, o);
                km = (oth > km) ? oth : km;
            }
            int sidx = 63 - (int)(km & 0xffffffffull);
            float esel = __shfl(e, sidx);
            if (lane == 0) {
                selpos_s[b][ts] = sidx;
                nscore_s[b][ts] = logf(esel / den + 1e-20f);
            }
            if (lane == sidx) mlc = -INFINITY;
        }
    }
    __syncthreads();
    // ---- phase 2: beam select on wave 0 (candidate c lives in lane c) ----
    if (wave == 0) {
        const int C = B * topk;
        float ac = 0.f, bc = 0.f;
        if (lane < C) {
            const int pb = lane / topk, ptt = lane - pb * topk;
            ac = accu[n*BEAM + pb] + nscore_s[pb][ptt];
            const float nb = done * ((ptt == 0) ? 1.f : 0.f) + (1.f - done);
            bc = bmask[n*BEAM + pb] * nb;
        }
        bool used = false;
        for (int k = 0; k < BEAM; ++k) {
            int bestc;
            if (do_bsel) {
                const float v = (lane < C && !used)
                                ? ((bc > 0.f) ? ac : -1e9f) : -INFINITY;
                unsigned fb = __float_as_uint(v);
                unsigned ok = (fb & 0x80000000u) ? ~fb : (fb | 0x80000000u);
                unsigned long long key =
                    ((unsigned long long)ok << 32) | (unsigned)(63 - lane);
                unsigned long long km = key;
                #pragma unroll
                for (int o = 32; o > 0; o >>= 1) {
                    unsigned long long oth = __shfl_xor(km, o);
                    km = (oth > km) ? oth : km;
                }
                bestc = 63 - (int)(km & 0xffffffffull);
            } else bestc = k;
            if (lane == bestc) used = true;
            const float av  = __shfl(ac, bestc);
            const float bv2 = __shfl(bc, bestc);
            const int pp = bestc / topk, ss = selpos_s[pp][bestc - pp * topk];
            if (lane == 0) {
                parent[n*BEAM + k] = pp;
                posb[n*BEAM + k]   = ss;
                par_s[k] = pp; pos_s[k] = ss;
                accu_out[n*BEAM + k] = av;
                bm_out[n*BEAM + k]   = bv2;
            }
        }
    }
    __syncthreads();
    // ---- phase 3: l/r arena row ids (threads 0..BEAM-1) ----
    if (t < BEAM) {
        const int base = (n*BAo + par_s[t]) * STo + pos_s[t];
        lrid[n*BEAM + t] = idxold[base];
        rrid[n*BEAM + t] = idxold[base + 1];
    }
    // ---- phase 4: wave k copies beam k's compacted score row ----
    if (dow && wave < BEAM) {
        const int k = wave;
        const int p = par_s[k], s = pos_s[k];
        if (lane < Snew) {
            float v = 0.f;
            if (lane < s - 1)      v = w[(n*BEAM + p)*S0 + lane];
            else if (lane > s)     v = w[(n*BEAM + p)*S0 + lane + 1];
            wnew[(n*BEAM + k)*S0 + lane] = v;
        }
    }
}

// ======== compose: sum ZSPLIT partials + gate softmax + mix + LN -> arena ========
__global__ __launch_bounds__(256) void k_compose(
    const float* __restrict__ P,
    const _Float16* __restrict__ cha_r, const _Float16* __restrict__ cla_r,
    const int* __restrict__ lrid, const int* __restrict__ rrid,
    const int* __restrict__ parent, const int* __restrict__ posb,
    const int* __restrict__ idxold, int BAo, int STo,
    const float* __restrict__ maskg, int iiter, int Spnew,
    const float* __restrict__ gp, const float* __restrict__ bp,
    _Float16* __restrict__ cha_w, _Float16* __restrict__ cla_w, int newbase,
    int* __restrict__ idxnew, int finalflag, float* __restrict__ nvout)
{
    __shared__ float sb[8];
    const int nk = blockIdx.x, t = threadIdx.x;
    const int n = nk / BEAM;
    size_t lbase, rbase;
    if (finalflag) {
        lbase = (size_t)idxold[nk*31 + 0] * 512;
        rbase = (size_t)idxold[nk*31 + 1] * 512;
    } else {
        lbase = (size_t)lrid[nk] * 512;
        rbase = (size_t)rrid[nk] * 512;
    }
    const float* c = P + (size_t)nk * CHID;
    float o[2];
    #pragma unroll
    for (int e = 0; e < 2; ++e) {
        const int d = t + 256*e;
        const float lv = recon(cha_r[lbase + d], cla_r[lbase + d]);
        const float rv = recon(cha_r[rbase + d], cla_r[rbase + d]);
        float c0 = c[d]        + c[MN2 + d];
        float c1 = c[DD + d]   + c[MN2 + DD + d];
        float c2 = c[2*DD + d] + c[MN2 + 2*DD + d];
        float c3 = c[3*DD + d] + c[MN2 + 3*DD + d];
        float m = fmaxf(c0, fmaxf(c1, c2));
        float e0 = expf(c0 - m), e1 = expf(c1 - m), e2 = expf(c2 - m);
        float inv = 1.f / (e0 + e1 + e2);
        o[e] = (e0*lv + e1*rv + e2*c3) * inv;
    }
    float s1 = block_reduce_sum(o[0] + o[1], sb);
    float s2 = block_reduce_sum(o[0]*o[0] + o[1]*o[1], sb);
    float mu = s1 * (1.f/512.f);
    float rstd = rsqrtf(s2 * (1.f/512.f) - mu*mu + 1e-5f);
    if (finalflag) {
        #pragma unroll
        for (int e = 0; e < 2; ++e) {
            const int d = t + 256*e;
            nvout[(size_t)nk*DD + d] = (o[e] - mu) * rstd * gp[d] + bp[d];
        }
        return;
    }
    const int arow = newbase + nk;
    #pragma unroll
    for (int e = 0; e < 2; ++e) {
        const int d = t + 256*e;
        float v = (o[e] - mu) * rstd * gp[d] + bp[d];
        _Float16 h = hi16(v);
        cha_w[(size_t)arow*512 + d] = h;
        cla_w[(size_t)arow*512 + d] = lo16(v, h);
    }
    if (t < Spnew) {
        const float done = maskg[n*S0 + iiter + 1];
        const int p = parent[nk], s = posb[nk];
        const int src = (n*BAo + p) * STo;
        int val;
        if (done > 0.5f)
            val = (t < s) ? idxold[src + t] : (t == s ? arow : idxold[src + t + 1]);
        else
            val = idxold[src + t];
        idxnew[nk*31 + t] = val;
    }
}

// ============ final beam softmax mix ============
__global__ __launch_bounds__(256) void k_final(
    const float* __restrict__ nv,
    const _Float16* __restrict__ cha, const _Float16* __restrict__ cla,
    const int* __restrict__ idxt, const float* __restrict__ maskg,
    const float* __restrict__ accu, const float* __restrict__ bmv,
    float* __restrict__ out)
{
    const int n = blockIdx.x, t = threadIdx.x;
    const float done = maskg[n*S0 + 31];
    float sc[BEAM];
    #pragma unroll
    for (int k = 0; k < BEAM; ++k) {
        float m = bmv[n*BEAM + k];
        sc[k] = m * accu[n*BEAM + k] + (1.f - m) * (-999999.f);
    }
    float mx = sc[0];
    #pragma unroll
    for (int k = 1; k < BEAM; ++k) mx = fmaxf(mx, sc[k]);
    float e[BEAM], den = 0.f;
    #pragma unroll
    for (int k = 0; k < BEAM; ++k) { e[k] = expf(sc[k] - mx); den += e[k]; }
    const float inv = 1.f / den;
    #pragma unroll
    for (int i2 = 0; i2 < 2; ++i2) {
        const int d = t + 256*i2;
        float s = 0.f;
        #pragma unroll
        for (int k = 0; k < BEAM; ++k) {
            const int nk = n*BEAM + k;
            const size_t ob = (size_t)idxt[nk*31] * 512;
            const float nvv  = nv[(size_t)nk*DD + d];
            const float oldv = recon(cha[ob + d], cla[ob + d]);
            s += e[k]*inv * (done*nvv + (1.f - done)*oldv);
        }
        out[(size_t)n*DD + d] = s;
    }
}

extern "C" void kernel_launch(void* const* d_in, const int* in_sizes, int n_in,
                              void* d_out, int out_size, void* d_ws, size_t ws_size,
                              hipStream_t stream) {
    (void)in_sizes; (void)n_in; (void)out_size; (void)ws_size;
    const float* x    = (const float*)d_in[0];
    const float* mask = (const float*)d_in[1];
    const float* Wi   = (const float*)d_in[2];
    const float* bi   = (const float*)d_in[3];
    const float* g1   = (const float*)d_in[4];
    const float* b1   = (const float*)d_in[5];
    const float* Wd1  = (const float*)d_in[6];
    const float* bd1  = (const float*)d_in[7];
    const float* Wd2  = (const float*)d_in[8];
    const float* bd2  = (const float*)d_in[9];
    const float* Wc1  = (const float*)d_in[10];
    const float* bc1  = (const float*)d_in[11];
    const float* Wc2  = (const float*)d_in[12];
    const float* bc2  = (const float*)d_in[13];
    const float* g2   = (const float*)d_in[14];
    const float* b2   = (const float*)d_in[15];
    float* out = (float*)d_out;

    // ---- workspace carve-up (bytes), ~185 MB ----
    char* p = (char*)d_ws;
    _Float16* cha = (_Float16*)p;        p += (size_t)AR_TOT*512*2;
    _Float16* cla = (_Float16*)p;        p += (size_t)AR_TOT*512*2;
    _Float16* Wc1th = (_Float16*)p;      p += (size_t)CHID*1024*2;
    _Float16* Wc1tl = (_Float16*)p;      p += (size_t)CHID*1024*2;
    _Float16* Wc2th = (_Float16*)p;      p += (size_t)CHID*CHID*2;
    _Float16* Wc2tl = (_Float16*)p;      p += (size_t)CHID*CHID*2;
    _Float16* Wd1th = (_Float16*)p;      p += (size_t)512*1024*2;
    _Float16* Wd1tl = (_Float16*)p;      p += (size_t)512*1024*2;
    _Float16* Wih = (_Float16*)p;        p += (size_t)WDIM*DD*2;
    _Float16* Wil = (_Float16*)p;        p += (size_t)WDIM*DD*2;
    _Float16* Hh  = (_Float16*)p;        p += (size_t)NB*CHID*2;
    _Float16* Hl  = (_Float16*)p;        p += (size_t)NB*CHID*2;
    float* Pb   = (float*)p;             p += MN2*4*4;                // slices
    float* nvb  = (float*)p;             p += (size_t)NB*DD*4;
    float* wA   = (float*)p;             p += (size_t)NB*S0*4;
    float* wB   = (float*)p;             p += (size_t)NB*S0*4;
    float* accA = (float*)p;             p += NB*4;
    float* accB = (float*)p;             p += NB*4;
    float* bmA  = (float*)p;             p += NB*4;
    float* bmB  = (float*)p;             p += NB*4;
    int* parent = (int*)p;               p += NB*4;
    int* posb   = (int*)p;               p += NB*4;
    int* lrid   = (int*)p;               p += NB*4;
    int* rrid   = (int*)p;               p += NB*4;
    int* idx0   = (int*)p;               p += AR_INIT*4;
    int* idxA   = (int*)p;               p += NB*31*4;
    int* idxB   = (int*)p;               p += NB*31*4;
    // init-only aliases inside Pb
    _Float16* xh = (_Float16*)Pb;
    _Float16* xl = (_Float16*)((char*)Pb + (size_t)AR_INIT*512*2);
    float* ybuf  = (float*)((char*)Pb + (size_t)AR_INIT*512*4);

    // ---- prep ----
    k_tsplit<<<dim3(CHID/32, 1024/32), 256, 0, stream>>>(Wc1, Wc1th, Wc1tl, 1024, CHID);
    k_tsplit<<<dim3(CHID/32, CHID/32), 256, 0, stream>>>(Wc2, Wc2th, Wc2tl, CHID, CHID);
    k_tsplit<<<dim3(512/32, 1024/32), 256, 0, stream>>>(Wd1, Wd1th, Wd1tl, 1024, 512);
    k_tsplit<<<dim3(DD/32, WDIM/32), 256, 0, stream>>>(Wi, Wih, Wil, WDIM, DD);
    k_init_state<<<(NB*S0 + 255)/256, 256, 0, stream>>>(accA, bmA, idx0, wA);

    // ---- init: arena rows 0..8191 = LN(x@Wi+bi) ----
    k_xsplit<<<(AR_INIT*WDIM)/1024, 256, 0, stream>>>(x, xh, xl);
    k_gemm<0><<<dim3(DD/128, AR_INIT/64, 1), 256, 0, stream>>>(
        xh, xl, Wih, Wil, bi, ybuf, AR_INIT, DD, WDIM, WDIM);
    k_ln_init<<<AR_INIT, 256, 0, stream>>>(ybuf, g1, b1, cha, cla);
    k_wscore<0><<<dim3(NN*31/64, 8), 256, 0, stream>>>(
        cha, cla, nullptr, nullptr, Wd1th, Wd1tl, bd1, Wd2, bd2, wA, 31);

    const int* idxcur = idx0;
    int* idxnxt = idxA;
    int BAo = 1, STo = 32;
    float *wcur = wA, *wnxt = wB;
    float *acur = accA, *anxt = accB, *bcur = bmA, *bnxt = bmB;
    for (int i = 0; i < 30; ++i) {
        const int B  = (i == 0) ? 1 : BEAM;
        const int S  = 31 - i;
        const int tk = (S < BEAM) ? S : BEAM;
        const int dob = (B*tk > BEAM) ? 1 : 0;
        const int newbase = AR_INIT + i*NB;
        k_topk<<<NN, 320, 0, stream>>>(wcur, acur, bcur, mask, i, B, S, tk, dob,
                                       idxcur, BAo, STo, parent, posb, lrid, rrid,
                                       anxt, bnxt, wnxt, S - 1, (i < 29) ? 1 : 0);
        k_gemm1<1><<<dim3(CHID/64, NB/64), 256, 0, stream>>>(
            cha, cla, Wc1th, Wc1tl, bc1, Hh, Hl, lrid, rrid, nullptr, CHID);
        k_gemm<0><<<dim3(CHID/128, NB/64, ZSPLIT), 256, 0, stream>>>(
            Hh, Hl, Wc2th, Wc2tl, bc2, Pb, NB, CHID, CHID, CHID/ZSPLIT);
        k_compose<<<NB, 256, 0, stream>>>(Pb, cha, cla, lrid, rrid, parent, posb,
                                          idxcur, BAo, STo, mask, i, 31 - i,
                                          g2, b2, cha, cla, newbase, idxnxt,
                                          0, nullptr);
        if (i < 29)
            k_wscore<1><<<dim3(NB*2/64, 8), 256, 0, stream>>>(
                cha, cla, posb, idxnxt, Wd1th, Wd1tl, bd1, Wd2, bd2, wnxt, S - 1);
        idxcur = idxnxt;
        idxnxt = (idxnxt == idxA) ? idxB : idxA;
        BAo = BEAM; STo = 31;
        float* tp;
        tp = wcur; wcur = wnxt; wnxt = tp;
        tp = acur; acur = anxt; anxt = tp;
        tp = bcur; bcur = bnxt; bnxt = tp;
    }
    // final compose: l,r = table positions 0,1
    k_gemm1<2><<<dim3(CHID/64, NB/64), 256, 0, stream>>>(
        cha, cla, Wc1th, Wc1tl, bc1, Hh, Hl, nullptr, nullptr, idxcur, CHID);
    k_gemm<0><<<dim3(CHID/128, NB/64, ZSPLIT), 256, 0, stream>>>(
        Hh, Hl, Wc2th, Wc2tl, bc2, Pb, NB, CHID, CHID, CHID/ZSPLIT);
    k_compose<<<NB, 256, 0, stream>>>(Pb, cha, cla, nullptr, nullptr, parent, posb,
                                      idxcur, BEAM, 31, mask, 30, 0,
                                      g2, b2, nullptr, nullptr, 0,
                                      nullptr, 1, nvb);
    k_final<<<NN, 256, 0, stream>>>(nvb, cha, cla, idxcur, mask, acur, bcur, out);
}

// Round 7
// 3428.733 us; speedup vs baseline: 1.2141x; 1.0225x over previous
//
#include <hip/hip_runtime.h>
#include <math.h>

// EBT_GRC beam-search forward, round 17: 512-thread k_gemm.
// r16 post-mortem: occupancy 8.5->18.4% but dur only 56->53.5us; per-CU pipe
// accounting shows LDS pipe ~60% busy (highest), yet r13's lower-LDS config
// was slower -> joint occupancy+LDS+barrier constraint. New point:
//  - k_gemm: 512 threads, 128x128 tile, 8 waves of 32x64 (same 72-VGPR
//    per-wave working set, same 0.5 reads/MFMA), 32KB/stage dbuf=64KB ->
//    2 blk/CU = 16 waves/CU cap; one barrier per 2x work. z back to 4
//    (grid 640, 5 work-blocks/CU over 2 resident = balanced).
//  - k_compose: sum 4 partial slices again (ZSPLIT=4).
//  - launch_bounds kept at (.,1) everywhere: (256,3)/(256,4) builds killed
//    the container twice (r4/r5) - never force min-waves on this toolchain.
//  - rest identical to r16 (3505.7us best).
// N=256, S=32, D=512, CH=2048, BEAM=5. WS ~185 MB.

#define NN   256
#define S0   32
#define WDIM 512
#define DD   512
#define CHID 2048
#define BEAM 5
#define NB   (NN*BEAM)   // 1280
#define RSCALE 2048.0f
#define RINV  (1.0f/2048.0f)
#define AR_INIT 8192
#define AR_TOT  (AR_INIT + 30*NB)    // 46592 rows
#define MN2 ((size_t)NB*CHID)        // partial-buffer slice stride
#define ZSPLIT 4

typedef __attribute__((ext_vector_type(8))) _Float16 f16x8;
typedef __attribute__((ext_vector_type(4))) float f32x4;

__device__ __forceinline__ float gelu_f(float x) {
    return 0.5f * x * (1.0f + erff(x * 0.7071067811865475f));
}
__device__ __forceinline__ _Float16 hi16(float v) { return (_Float16)v; }
__device__ __forceinline__ _Float16 lo16(float v, _Float16 h) {
    return (_Float16)((v - (float)h) * RSCALE);
}
__device__ __forceinline__ float recon(_Float16 h, _Float16 l) {
    return (float)h + RINV * (float)l;
}

__device__ __forceinline__ void gload_lds16(const void* g, void* l) {
    __builtin_amdgcn_global_load_lds(
        (const __attribute__((address_space(1))) unsigned*)g,
        (__attribute__((address_space(3))) unsigned*)l, 16, 0, 0);
}

__device__ __forceinline__ float block_reduce_sum(float v, float* sb) {
    #pragma unroll
    for (int o = 32; o > 0; o >>= 1) v += __shfl_down(v, o);
    const int lane = threadIdx.x & 63, wid = threadIdx.x >> 6;
    __syncthreads();
    if (lane == 0) sb[wid] = v;
    __syncthreads();
    return sb[0] + sb[1] + sb[2] + sb[3];
}

// == fp16x2 split MFMA GEMM, 128x128 tile, 512 thr (8 waves 32x64), split-K ==
template<int AIDX>
__global__ __launch_bounds__(512, 1) void k_gemm(
    const _Float16* __restrict__ Ah, const _Float16* __restrict__ Al,
    const _Float16* __restrict__ Bh, const _Float16* __restrict__ Bl,
    const float* __restrict__ bias, float* __restrict__ Cf,
    int M, int N, int Ktot, int Kchunk)
{
    // per stage (halves): Ah[0,4096) Al[4096,8192) Bh[8192,12288) Bl[12288,16384)
    __shared__ __align__(16) _Float16 lds[2][16384];   // 64 KB dbuf
    const int t = threadIdx.x, wave = t >> 6, lane = t & 63;
    const int bm = blockIdx.y * 128, bn = blockIdx.x * 128;
    const int koff = blockIdx.z * Kchunk;
    const int wm = (wave >> 1) * 32, wn = (wave & 1) * 64;   // wave tile 32x64
    const int rsub = lane >> 2, seg = lane & 3;
    const int fm = lane & 15, quad = lane >> 4, fko = quad * 8;

    f32x4 acc0[2][4], acc1[2][4];
    #pragma unroll
    for (int i = 0; i < 2; ++i)
        #pragma unroll
        for (int j = 0; j < 4; ++j) {
            acc0[i][j] = (f32x4){0.f, 0.f, 0.f, 0.f};
            acc1[i][j] = (f32x4){0.f, 0.f, 0.f, 0.f};
        }

    const int iters = Kchunk >> 5;
    // 4 global_load_lds per wave per stage: A rows / B rows [wave*16, +16)
    #define STAGE_G(IT, BUF) {                                                 \
        const int k = koff + (IT)*32;                                          \
        _Float16* Lb = &lds[BUF][0];                                           \
        const size_t aoff = (size_t)(bm + wave*16 + rsub) * Ktot + k + seg*8;  \
        const size_t boff = (size_t)(bn + wave*16 + rsub) * Ktot + k + seg*8;  \
        gload_lds16(Ah + aoff, Lb + wave*512);                                 \
        gload_lds16(Al + aoff, Lb + 4096 + wave*512);                          \
        gload_lds16(Bh + boff, Lb + 8192 + wave*512);                          \
        gload_lds16(Bl + boff, Lb + 12288 + wave*512);                         \
    }

    STAGE_G(0, 0);
    for (int it = 0; it < iters; ++it) {
        __syncthreads();
        if (it + 1 < iters) STAGE_G(it + 1, (it + 1) & 1);
        const _Float16* L = &lds[it & 1][0];
        f16x8 ah[2], al[2];
        #pragma unroll
        for (int i = 0; i < 2; ++i) {
            const int ar = wm + i*16 + fm;
            ah[i] = *(const f16x8*)&L[ar*32 + fko];
            al[i] = *(const f16x8*)&L[4096 + ar*32 + fko];
        }
        #pragma unroll
        for (int j = 0; j < 4; ++j) {
            const int br = wn + j*16 + fm;
            f16x8 bh = *(const f16x8*)&L[8192 + br*32 + fko];
            f16x8 bl = *(const f16x8*)&L[12288 + br*32 + fko];
            #pragma unroll
            for (int i = 0; i < 2; ++i) {
                acc0[i][j] = __builtin_amdgcn_mfma_f32_16x16x32_f16(ah[i], bh, acc0[i][j], 0, 0, 0);
                acc1[i][j] = __builtin_amdgcn_mfma_f32_16x16x32_f16(ah[i], bl, acc1[i][j], 0, 0, 0);
                acc1[i][j] = __builtin_amdgcn_mfma_f32_16x16x32_f16(al[i], bh, acc1[i][j], 0, 0, 0);
            }
        }
    }
    float* dst = Cf + (size_t)blockIdx.z * M * N;
    #pragma unroll
    for (int i = 0; i < 2; ++i)
        #pragma unroll
        for (int j = 0; j < 4; ++j) {
            const int col = bn + wn + j*16 + fm;
            const float bv = (blockIdx.z == 0) ? bias[col] : 0.f;
            #pragma unroll
            for (int r = 0; r < 4; ++r) {
                const int row = bm + wm + i*16 + quad*4 + r;
                dst[(size_t)row * N + col] = acc0[i][j][r] + acc1[i][j][r] * RINV + bv;
            }
        }
    #undef STAGE_G
}

// ==== GEMM1 fused: H = gelu(cat@Wc1+bc1) -> fp16 h/l, 64x64 tiles, dbuf ====
template<int AIDX>
__global__ __launch_bounds__(256, 1) void k_gemm1(
    const _Float16* __restrict__ Ah, const _Float16* __restrict__ Al,
    const _Float16* __restrict__ Bh, const _Float16* __restrict__ Bl,
    const float* __restrict__ bias,
    _Float16* __restrict__ Oh, _Float16* __restrict__ Ol,
    const int* __restrict__ lrid, const int* __restrict__ rrid,
    const int* __restrict__ idxt, int N)
{
    // per stage: Ah[0,2048) Al[2048,4096) Bh[4096,6144) Bl[6144,8192) halves
    __shared__ __align__(16) _Float16 lds[2][8192];   // 32 KB
    const int t = threadIdx.x, wave = t >> 6, lane = t & 63;
    const int bm = blockIdx.y * 64, bn = blockIdx.x * 64;
    const int rsub = lane >> 2, seg = lane & 3;
    const int fm = lane & 15, quad = lane >> 4, fko = quad * 8;
    const int wr = wave >> 1, wc = wave & 1;   // wave tile 32x32

    size_t lb, rb;
    {
        const int rowm = bm + wave*16 + rsub;
        if (AIDX == 1) {
            lb = (size_t)lrid[rowm] * 512;
            rb = (size_t)rrid[rowm] * 512;
        } else {
            lb = (size_t)idxt[rowm*31 + 0] * 512;
            rb = (size_t)idxt[rowm*31 + 1] * 512;
        }
    }
    const size_t bbase = (size_t)(bn + wave*16 + rsub) * 1024;

    f32x4 acc0[2][2], acc1[2][2];
    #pragma unroll
    for (int i = 0; i < 2; ++i)
        #pragma unroll
        for (int j = 0; j < 2; ++j) {
            acc0[i][j] = (f32x4){0.f, 0.f, 0.f, 0.f};
            acc1[i][j] = (f32x4){0.f, 0.f, 0.f, 0.f};
        }

    // 4 global_load_lds per wave per stage
    #define STAGE_G1(IT, BUF) {                                                 \
        const int k0 = (IT)*32;                                                 \
        _Float16* Lb = &lds[BUF][0];                                            \
        const size_t aoff = (k0 < 512 ? lb + k0 : rb + (k0-512)) + seg*8;       \
        gload_lds16(Ah + aoff, Lb + wave*512);                                  \
        gload_lds16(Al + aoff, Lb + 2048 + wave*512);                           \
        gload_lds16(Bh + bbase + k0 + seg*8, Lb + 4096 + wave*512);             \
        gload_lds16(Bl + bbase + k0 + seg*8, Lb + 6144 + wave*512); }

    STAGE_G1(0, 0);
    for (int it = 0; it < 32; ++it) {
        __syncthreads();
        if (it + 1 < 32) STAGE_G1(it + 1, (it + 1) & 1);
        const _Float16* L = &lds[it & 1][0];
        f16x8 ah[2], al[2];
        #pragma unroll
        for (int i = 0; i < 2; ++i) {
            const int ar = wr*32 + i*16 + fm;
            ah[i] = *(const f16x8*)&L[ar*32 + fko];
            al[i] = *(const f16x8*)&L[2048 + ar*32 + fko];
        }
        #pragma unroll
        for (int j = 0; j < 2; ++j) {
            const int br = wc*32 + j*16 + fm;
            f16x8 bh = *(const f16x8*)&L[4096 + br*32 + fko];
            f16x8 bl = *(const f16x8*)&L[6144 + br*32 + fko];
            #pragma unroll
            for (int i = 0; i < 2; ++i) {
                acc0[i][j] = __builtin_amdgcn_mfma_f32_16x16x32_f16(ah[i], bh, acc0[i][j], 0, 0, 0);
                acc1[i][j] = __builtin_amdgcn_mfma_f32_16x16x32_f16(ah[i], bl, acc1[i][j], 0, 0, 0);
                acc1[i][j] = __builtin_amdgcn_mfma_f32_16x16x32_f16(al[i], bh, acc1[i][j], 0, 0, 0);
            }
        }
    }
    #pragma unroll
    for (int i = 0; i < 2; ++i)
        #pragma unroll
        for (int j = 0; j < 2; ++j) {
            const int col = bn + wc*32 + j*16 + fm;
            const float bv = bias[col];
            #pragma unroll
            for (int r = 0; r < 4; ++r) {
                const int row = bm + wr*32 + i*16 + quad*4 + r;
                float v = gelu_f(acc0[i][j][r] + acc1[i][j][r] * RINV + bv);
                _Float16 h = hi16(v);
                Oh[(size_t)row * N + col] = h;
                Ol[(size_t)row * N + col] = lo16(v, h);
            }
        }
    #undef STAGE_G1
}

// ====== fused score (64x64 tiles, dbuf): w += gelu(cat@Wd1+bd1)@Wd2 ======
template<int MODE>
__global__ __launch_bounds__(256, 2) void k_wscore(
    const _Float16* __restrict__ ch, const _Float16* __restrict__ cl,
    const int* __restrict__ posb, const int* __restrict__ idxt,
    const _Float16* __restrict__ Bh, const _Float16* __restrict__ Bl,
    const float* __restrict__ bd1, const float* __restrict__ u512,
    const float* __restrict__ bd2, float* __restrict__ w, int Spairs)
{
    __shared__ __align__(16) _Float16 lds[2][8192];   // 32 KB
    const int t = threadIdx.x, wave = t >> 6, lane = t & 63;
    const int bm = blockIdx.x * 64, ncol0 = blockIdx.y * 64;
    const int rsub = lane >> 2, seg = lane & 3;
    const int fm = lane & 15, quad = lane >> 4, fko = quad * 8;

    size_t lb, rb;
    {
        const int rowm = bm + wave*16 + rsub;
        int lrow, rrow;
        if (MODE == 0) {
            const int n = rowm / 31, s = rowm - n * 31;
            lrow = n*32 + s; rrow = lrow + 1;
        } else {
            const int nk = rowm >> 1, slot = rowm & 1;
            const int s = posb[nk];
            int jw = s - 1 + slot;
            int jc = jw < 0 ? 0 : (jw > Spairs - 1 ? Spairs - 1 : jw);
            lrow = idxt[nk*31 + jc]; rrow = idxt[nk*31 + jc + 1];
        }
        lb = (size_t)lrow * 512; rb = (size_t)rrow * 512;
    }
    const size_t bbase = (size_t)(ncol0 + wave*16 + rsub) * 1024;

    f32x4 acc0[4], acc1[4];
    #pragma unroll
    for (int j = 0; j < 4; ++j) {
        acc0[j] = (f32x4){0.f, 0.f, 0.f, 0.f};
        acc1[j] = (f32x4){0.f, 0.f, 0.f, 0.f};
    }
    #define STAGE_WS(IT, BUF) {                                                \
        const int k0 = (IT)*32;                                                \
        _Float16* Lb = &lds[BUF][0];                                           \
        const size_t aoff = (k0 < 512 ? lb + k0 : rb + (k0-512)) + seg*8;      \
        gload_lds16(ch + aoff, Lb + 0*2048 + wave*512);                        \
        gload_lds16(cl + aoff, Lb + 1*2048 + wave*512);                        \
        gload_lds16(Bh + bbase + k0 + seg*8, Lb + 2*2048 + wave*512);          \
        gload_lds16(Bl + bbase + k0 + seg*8, Lb + 3*2048 + wave*512); }

    STAGE_WS(0, 0);
    for (int it = 0; it < 32; ++it) {
        __syncthreads();
        if (it + 1 < 32) STAGE_WS(it + 1, (it + 1) & 1);
        const _Float16* L = &lds[it & 1][0];
        const int ar = wave*16 + fm;
        f16x8 ah = *(const f16x8*)&L[0*2048 + ar*32 + fko];
        f16x8 al = *(const f16x8*)&L[1*2048 + ar*32 + fko];
        #pragma unroll
        for (int j = 0; j < 4; ++j) {
            const int br = j*16 + fm;
            f16x8 bh = *(const f16x8*)&L[2*2048 + br*32 + fko];
            f16x8 bl = *(const f16x8*)&L[3*2048 + br*32 + fko];
            acc0[j] = __builtin_amdgcn_mfma_f32_16x16x32_f16(ah, bh, acc0[j], 0, 0, 0);
            acc1[j] = __builtin_amdgcn_mfma_f32_16x16x32_f16(ah, bl, acc1[j], 0, 0, 0);
            acc1[j] = __builtin_amdgcn_mfma_f32_16x16x32_f16(al, bh, acc1[j], 0, 0, 0);
        }
    }
    float part[4] = {0.f, 0.f, 0.f, 0.f};
    #pragma unroll
    for (int j = 0; j < 4; ++j) {
        const int col = ncol0 + j*16 + fm;
        const float bv = bd1[col], uv = u512[col];
        #pragma unroll
        for (int r = 0; r < 4; ++r) {
            float v = acc0[j][r] + acc1[j][r] * RINV + bv;
            part[r] += gelu_f(v) * uv;
        }
    }
    #pragma unroll
    for (int r = 0; r < 4; ++r) {
        float s = part[r];
        s += __shfl_xor(s, 1); s += __shfl_xor(s, 2);
        s += __shfl_xor(s, 4); s += __shfl_xor(s, 8);
        part[r] = s;
    }
    if (fm == 0) {
        const float bd2v = (blockIdx.y == 0) ? bd2[0] : 0.f;
        #pragma unroll
        for (int r = 0; r < 4; ++r) {
            const int rowm = bm + wave*16 + quad*4 + r;
            int wi = -1;
            if (MODE == 0) {
                const int n = rowm / 31, s = rowm - n * 31;
                wi = n * BEAM * S0 + s;
            } else {
                const int nk = rowm >> 1, slot = rowm & 1;
                const int jw = posb[nk] - 1 + slot;
                if (jw >= 0 && jw < Spairs) wi = nk * S0 + jw;
            }
            if (wi >= 0) atomicAdd(&w[wi], part[r] + bd2v);
        }
    }
    #undef STAGE_WS
}

// ============ weight transpose + fp16 split ============
__global__ __launch_bounds__(256) void k_tsplit(
    const float* __restrict__ in, _Float16* __restrict__ oh,
    _Float16* __restrict__ ol, int K, int N)
{
    __shared__ float tile[32][33];
    const int bx = blockIdx.x * 32, by = blockIdx.y * 32;
    const int t = threadIdx.x, r = t >> 5, c = t & 31;
    #pragma unroll
    for (int p = 0; p < 4; ++p)
        tile[r + p*8][c] = in[(size_t)(by + r + p*8) * N + bx + c];
    __syncthreads();
    #pragma unroll
    for (int p = 0; p < 4; ++p) {
        const int nl = r + p*8;
        float v = tile[c][nl];
        _Float16 h = hi16(v);
        oh[(size_t)(bx + nl) * K + by + c] = h;
        ol[(size_t)(bx + nl) * K + by + c] = lo16(v, h);
    }
}

// ============ elementwise fp16 split (x rows, init only) ============
__global__ __launch_bounds__(256) void k_xsplit(
    const float* __restrict__ in, _Float16* __restrict__ oh,
    _Float16* __restrict__ ol)
{
    const size_t i = ((size_t)blockIdx.x * 256 + threadIdx.x) * 4;
    float4 v = *(const float4*)(in + i);
    _Float16 h0 = hi16(v.x), h1 = hi16(v.y), h2 = hi16(v.z), h3 = hi16(v.w);
    typedef __attribute__((ext_vector_type(4))) _Float16 f16x4v;
    f16x4v h = {h0, h1, h2, h3};
    f16x4v l = {lo16(v.x,h0), lo16(v.y,h1), lo16(v.z,h2), lo16(v.w,h3)};
    *(f16x4v*)(oh + i) = h;
    *(f16x4v*)(ol + i) = l;
}

// ============ init layernorm -> split arena rows ============
__global__ __launch_bounds__(256) void k_ln_init(
    const float* __restrict__ y, const float* __restrict__ g,
    const float* __restrict__ b, _Float16* __restrict__ cha,
    _Float16* __restrict__ cla)
{
    const int row = blockIdx.x;
    const float* yr = y + (size_t)row * DD;
    const int t = threadIdx.x;
    float v0 = yr[t], v1 = yr[t + 256];
    __shared__ float sb[8];
    float s1 = block_reduce_sum(v0 + v1, sb);
    float s2 = block_reduce_sum(v0*v0 + v1*v1, sb);
    float mu = s1 * (1.f/512.f);
    float rstd = rsqrtf(s2 * (1.f/512.f) - mu*mu + 1e-5f);
    float a0 = (v0 - mu) * rstd * g[t]       + b[t];
    float a1 = (v1 - mu) * rstd * g[t + 256] + b[t + 256];
    _Float16 h0 = hi16(a0), h1 = hi16(a1);
    cha[(size_t)row*DD + t]       = h0;
    cla[(size_t)row*DD + t]       = lo16(a0, h0);
    cha[(size_t)row*DD + t + 256] = h1;
    cla[(size_t)row*DD + t + 256] = lo16(a1, h1);
}

__global__ void k_init_state(float* accu, float* bm, int* idx0, float* wz) {
    int i = blockIdx.x * blockDim.x + threadIdx.x;
    if (i < NB*S0) wz[i] = 0.f;
    if (i < AR_INIT) idx0[i] = i;
    if (i < NB) { accu[i] = 0.f; bm[i] = 1.f; }
}

// ====== top-k (5 waves: wave b = beam b) + beam select + l/r row ids ======
__global__ __launch_bounds__(320) void k_topk(
    const float* __restrict__ w, const float* __restrict__ accu,
    const float* __restrict__ bmask, const float* __restrict__ maskg,
    int iiter, int B, int S, int topk, int do_bsel,
    const int* __restrict__ idxold, int BAo, int STo,
    int* __restrict__ parent, int* __restrict__ posb,
    int* __restrict__ lrid, int* __restrict__ rrid,
    float* __restrict__ accu_out, float* __restrict__ bm_out,
    float* __restrict__ wnew, int Snew, int dow)
{
    const int n = blockIdx.x, t = threadIdx.x;
    const int wave = t >> 6, lane = t & 63;
    __shared__ int   selpos_s[BEAM][BEAM];
    __shared__ float nscore_s[BEAM][BEAM];
    __shared__ int   par_s[BEAM], pos_s[BEAM];
    const float* mrow = maskg + n*S0 + (iiter + 1);
    const float mk   = (lane < S) ? mrow[lane] : 0.f;
    const float done = 1.f - mrow[0];
    // ---- phase 1: wave b computes beam b's masked softmax + top-k ----
    if (wave < B) {
        const int b = wave;
        float ml;
        if (lane < S) {
            float wv = w[(n*BEAM + b)*S0 + lane];
            ml = (mk > 0.f) ? wv : -1e9f;
        } else ml = -INFINITY;
        float mx = ml;
        #pragma unroll
        for (int o = 32; o > 0; o >>= 1) mx = fmaxf(mx, __shfl_xor(mx, o));
        float e = (lane < S) ? expf(ml - mx) * mk : 0.f;
        float es = e;
        #pragma unroll
        for (int o = 32; o > 0; o >>= 1) es += __shfl_xor(es, o);
        const float den = es + 1e-20f;
        float mlc = ml;
        for (int ts = 0; ts < topk; ++ts) {
            unsigned int fb = __float_as_uint(mlc);
            unsigned int ok = (fb & 0x80000000u) ? ~fb : (fb | 0x80000000u);
            unsigned long long key =
                ((unsigned long long)ok << 32) | (unsigned int)(63 - lane);
            if (lane >= S) key = 0ull;
            unsigned long long km = key;
            #pragma unroll
            for (int o = 32; o > 0; o >>= 1) {
                unsigned long long oth = __shfl_xor(km, o);
                km = (oth > km) ? oth : km;
            }
            int sidx = 63 - (int)(km & 0xffffffffull);
            float esel = __shfl(e, sidx);
            if (lane == 0) {
                selpos_s[b][ts] = sidx;
                nscore_s[b][ts] = logf(esel / den + 1e-20f);
            }
            if (lane == sidx) mlc = -INFINITY;
        }
    }
    __syncthreads();
    // ---- phase 2: beam select on wave 0 (candidate c lives in lane c) ----
    if (wave == 0) {
        const int C = B * topk;
        float ac = 0.f, bc = 0.f;
        if (lane < C) {
            const int pb = lane / topk, ptt = lane - pb * topk;
            ac = accu[n*BEAM + pb] + nscore_s[pb][ptt];
            const float nb = done * ((ptt == 0) ? 1.f : 0.f) + (1.f - done);
            bc = bmask[n*BEAM + pb] * nb;
        }
        bool used = false;
        for (int k = 0; k < BEAM; ++k) {
            int bestc;
            if (do_bsel) {
                const float v = (lane < C && !used)
                                ? ((bc > 0.f) ? ac : -1e9f) : -INFINITY;
                unsigned fb = __float_as_uint(v);
                unsigned ok = (fb & 0x80000000u) ? ~fb : (fb | 0x80000000u);
                unsigned long long key =
                    ((unsigned long long)ok << 32) | (unsigned)(63 - lane);
                unsigned long long km = key;
                #pragma unroll
                for (int o = 32; o > 0; o >>= 1) {
                    unsigned long long oth = __shfl_xor(km, o);
                    km = (oth > km) ? oth : km;
                }
                bestc = 63 - (int)(km & 0xffffffffull);
            } else bestc = k;
            if (lane == bestc) used = true;
            const float av  = __shfl(ac, bestc);
            const float bv2 = __shfl(bc, bestc);
            const int pp = bestc / topk, ss = selpos_s[pp][bestc - pp * topk];
            if (lane == 0) {
                parent[n*BEAM + k] = pp;
                posb[n*BEAM + k]   = ss;
                par_s[k] = pp; pos_s[k] = ss;
                accu_out[n*BEAM + k] = av;
                bm_out[n*BEAM + k]   = bv2;
            }
        }
    }
    __syncthreads();
    // ---- phase 3: l/r arena row ids (threads 0..BEAM-1) ----
    if (t < BEAM) {
        const int base = (n*BAo + par_s[t]) * STo + pos_s[t];
        lrid[n*BEAM + t] = idxold[base];
        rrid[n*BEAM + t] = idxold[base + 1];
    }
    // ---- phase 4: wave k copies beam k's compacted score row ----
    if (dow && wave < BEAM) {
        const int k = wave;
        const int p = par_s[k], s = pos_s[k];
        if (lane < Snew) {
            float v = 0.f;
            if (lane < s - 1)      v = w[(n*BEAM + p)*S0 + lane];
            else if (lane > s)     v = w[(n*BEAM + p)*S0 + lane + 1];
            wnew[(n*BEAM + k)*S0 + lane] = v;
        }
    }
}

// ======== compose: sum ZSPLIT partials + gate softmax + mix + LN -> arena ========
__global__ __launch_bounds__(256) void k_compose(
    const float* __restrict__ P,
    const _Float16* __restrict__ cha_r, const _Float16* __restrict__ cla_r,
    const int* __restrict__ lrid, const int* __restrict__ rrid,
    const int* __restrict__ parent, const int* __restrict__ posb,
    const int* __restrict__ idxold, int BAo, int STo,
    const float* __restrict__ maskg, int iiter, int Spnew,
    const float* __restrict__ gp, const float* __restrict__ bp,
    _Float16* __restrict__ cha_w, _Float16* __restrict__ cla_w, int newbase,
    int* __restrict__ idxnew, int finalflag, float* __restrict__ nvout)
{
    __shared__ float sb[8];
    const int nk = blockIdx.x, t = threadIdx.x;
    const int n = nk / BEAM;
    size_t lbase, rbase;
    if (finalflag) {
        lbase = (size_t)idxold[nk*31 + 0] * 512;
        rbase = (size_t)idxold[nk*31 + 1] * 512;
    } else {
        lbase = (size_t)lrid[nk] * 512;
        rbase = (size_t)rrid[nk] * 512;
    }
    const float* c = P + (size_t)nk * CHID;
    float o[2];
    #pragma unroll
    for (int e = 0; e < 2; ++e) {
        const int d = t + 256*e;
        const float lv = recon(cha_r[lbase + d], cla_r[lbase + d]);
        const float rv = recon(cha_r[rbase + d], cla_r[rbase + d]);
        float c0 = ((c[d]        + c[MN2 + d])        + c[2*MN2 + d])        + c[3*MN2 + d];
        float c1 = ((c[DD + d]   + c[MN2 + DD + d])   + c[2*MN2 + DD + d])   + c[3*MN2 + DD + d];
        float c2 = ((c[2*DD + d] + c[MN2 + 2*DD + d]) + c[2*MN2 + 2*DD + d]) + c[3*MN2 + 2*DD + d];
        float c3 = ((c[3*DD + d] + c[MN2 + 3*DD + d]) + c[2*MN2 + 3*DD + d]) + c[3*MN2 + 3*DD + d];
        float m = fmaxf(c0, fmaxf(c1, c2));
        float e0 = expf(c0 - m), e1 = expf(c1 - m), e2 = expf(c2 - m);
        float inv = 1.f / (e0 + e1 + e2);
        o[e] = (e0*lv + e1*rv + e2*c3) * inv;
    }
    float s1 = block_reduce_sum(o[0] + o[1], sb);
    float s2 = block_reduce_sum(o[0]*o[0] + o[1]*o[1], sb);
    float mu = s1 * (1.f/512.f);
    float rstd = rsqrtf(s2 * (1.f/512.f) - mu*mu + 1e-5f);
    if (finalflag) {
        #pragma unroll
        for (int e = 0; e < 2; ++e) {
            const int d = t + 256*e;
            nvout[(size_t)nk*DD + d] = (o[e] - mu) * rstd * gp[d] + bp[d];
        }
        return;
    }
    const int arow = newbase + nk;
    #pragma unroll
    for (int e = 0; e < 2; ++e) {
        const int d = t + 256*e;
        float v = (o[e] - mu) * rstd * gp[d] + bp[d];
        _Float16 h = hi16(v);
        cha_w[(size_t)arow*512 + d] = h;
        cla_w[(size_t)arow*512 + d] = lo16(v, h);
    }
    if (t < Spnew) {
        const float done = maskg[n*S0 + iiter + 1];
        const int p = parent[nk], s = posb[nk];
        const int src = (n*BAo + p) * STo;
        int val;
        if (done > 0.5f)
            val = (t < s) ? idxold[src + t] : (t == s ? arow : idxold[src + t + 1]);
        else
            val = idxold[src + t];
        idxnew[nk*31 + t] = val;
    }
}

// ============ final beam softmax mix ============
__global__ __launch_bounds__(256) void k_final(
    const float* __restrict__ nv,
    const _Float16* __restrict__ cha, const _Float16* __restrict__ cla,
    const int* __restrict__ idxt, const float* __restrict__ maskg,
    const float* __restrict__ accu, const float* __restrict__ bmv,
    float* __restrict__ out)
{
    const int n = blockIdx.x, t = threadIdx.x;
    const float done = maskg[n*S0 + 31];
    float sc[BEAM];
    #pragma unroll
    for (int k = 0; k < BEAM; ++k) {
        float m = bmv[n*BEAM + k];
        sc[k] = m * accu[n*BEAM + k] + (1.f - m) * (-999999.f);
    }
    float mx = sc[0];
    #pragma unroll
    for (int k = 1; k < BEAM; ++k) mx = fmaxf(mx, sc[k]);
    float e[BEAM], den = 0.f;
    #pragma unroll
    for (int k = 0; k < BEAM; ++k) { e[k] = expf(sc[k] - mx); den += e[k]; }
    const float inv = 1.f / den;
    #pragma unroll
    for (int i2 = 0; i2 < 2; ++i2) {
        const int d = t + 256*i2;
        float s = 0.f;
        #pragma unroll
        for (int k = 0; k < BEAM; ++k) {
            const int nk = n*BEAM + k;
            const size_t ob = (size_t)idxt[nk*31] * 512;
            const float nvv  = nv[(size_t)nk*DD + d];
            const float oldv = recon(cha[ob + d], cla[ob + d]);
            s += e[k]*inv * (done*nvv + (1.f - done)*oldv);
        }
        out[(size_t)n*DD + d] = s;
    }
}

extern "C" void kernel_launch(void* const* d_in, const int* in_sizes, int n_in,
                              void* d_out, int out_size, void* d_ws, size_t ws_size,
                              hipStream_t stream) {
    (void)in_sizes; (void)n_in; (void)out_size; (void)ws_size;
    const float* x    = (const float*)d_in[0];
    const float* mask = (const float*)d_in[1];
    const float* Wi   = (const float*)d_in[2];
    const float* bi   = (const float*)d_in[3];
    const float* g1   = (const float*)d_in[4];
    const float* b1   = (const float*)d_in[5];
    const float* Wd1  = (const float*)d_in[6];
    const float* bd1  = (const float*)d_in[7];
    const float* Wd2  = (const float*)d_in[8];
    const float* bd2  = (const float*)d_in[9];
    const float* Wc1  = (const float*)d_in[10];
    const float* bc1  = (const float*)d_in[11];
    const float* Wc2  = (const float*)d_in[12];
    const float* bc2  = (const float*)d_in[13];
    const float* g2   = (const float*)d_in[14];
    const float* b2   = (const float*)d_in[15];
    float* out = (float*)d_out;

    // ---- workspace carve-up (bytes), ~185 MB ----
    char* p = (char*)d_ws;
    _Float16* cha = (_Float16*)p;        p += (size_t)AR_TOT*512*2;
    _Float16* cla = (_Float16*)p;        p += (size_t)AR_TOT*512*2;
    _Float16* Wc1th = (_Float16*)p;      p += (size_t)CHID*1024*2;
    _Float16* Wc1tl = (_Float16*)p;      p += (size_t)CHID*1024*2;
    _Float16* Wc2th = (_Float16*)p;      p += (size_t)CHID*CHID*2;
    _Float16* Wc2tl = (_Float16*)p;      p += (size_t)CHID*CHID*2;
    _Float16* Wd1th = (_Float16*)p;      p += (size_t)512*1024*2;
    _Float16* Wd1tl = (_Float16*)p;      p += (size_t)512*1024*2;
    _Float16* Wih = (_Float16*)p;        p += (size_t)WDIM*DD*2;
    _Float16* Wil = (_Float16*)p;        p += (size_t)WDIM*DD*2;
    _Float16* Hh  = (_Float16*)p;        p += (size_t)NB*CHID*2;
    _Float16* Hl  = (_Float16*)p;        p += (size_t)NB*CHID*2;
    float* Pb   = (float*)p;             p += MN2*4*4;                // 4 slices
    float* nvb  = (float*)p;             p += (size_t)NB*DD*4;
    float* wA   = (float*)p;             p += (size_t)NB*S0*4;
    float* wB   = (float*)p;             p += (size_t)NB*S0*4;
    float* accA = (float*)p;             p += NB*4;
    float* accB = (float*)p;             p += NB*4;
    float* bmA  = (float*)p;             p += NB*4;
    float* bmB  = (float*)p;             p += NB*4;
    int* parent = (int*)p;               p += NB*4;
    int* posb   = (int*)p;               p += NB*4;
    int* lrid   = (int*)p;               p += NB*4;
    int* rrid   = (int*)p;               p += NB*4;
    int* idx0   = (int*)p;               p += AR_INIT*4;
    int* idxA   = (int*)p;               p += NB*31*4;
    int* idxB   = (int*)p;               p += NB*31*4;
    // init-only aliases inside Pb
    _Float16* xh = (_Float16*)Pb;
    _Float16* xl = (_Float16*)((char*)Pb + (size_t)AR_INIT*512*2);
    float* ybuf  = (float*)((char*)Pb + (size_t)AR_INIT*512*4);

    // ---- prep ----
    k_tsplit<<<dim3(CHID/32, 1024/32), 256, 0, stream>>>(Wc1, Wc1th, Wc1tl, 1024, CHID);
    k_tsplit<<<dim3(CHID/32, CHID/32), 256, 0, stream>>>(Wc2, Wc2th, Wc2tl, CHID, CHID);
    k_tsplit<<<dim3(512/32, 1024/32), 256, 0, stream>>>(Wd1, Wd1th, Wd1tl, 1024, 512);
    k_tsplit<<<dim3(DD/32, WDIM/32), 256, 0, stream>>>(Wi, Wih, Wil, WDIM, DD);
    k_init_state<<<(NB*S0 + 255)/256, 256, 0, stream>>>(accA, bmA, idx0, wA);

    // ---- init: arena rows 0..8191 = LN(x@Wi+bi) ----
    k_xsplit<<<(AR_INIT*WDIM)/1024, 256, 0, stream>>>(x, xh, xl);
    k_gemm<0><<<dim3(DD/128, AR_INIT/128, 1), 512, 0, stream>>>(
        xh, xl, Wih, Wil, bi, ybuf, AR_INIT, DD, WDIM, WDIM);
    k_ln_init<<<AR_INIT, 256, 0, stream>>>(ybuf, g1, b1, cha, cla);
    k_wscore<0><<<dim3(NN*31/64, 8), 256, 0, stream>>>(
        cha, cla, nullptr, nullptr, Wd1th, Wd1tl, bd1, Wd2, bd2, wA, 31);

    const int* idxcur = idx0;
    int* idxnxt = idxA;
    int BAo = 1, STo = 32;
    float *wcur = wA, *wnxt = wB;
    float *acur = accA, *anxt = accB, *bcur = bmA, *bnxt = bmB;
    for (int i = 0; i < 30; ++i) {
        const int B  = (i == 0) ? 1 : BEAM;
        const int S  = 31 - i;
        const int tk = (S < BEAM) ? S : BEAM;
        const int dob = (B*tk > BEAM) ? 1 : 0;
        const int newbase = AR_INIT + i*NB;
        k_topk<<<NN, 320, 0, stream>>>(wcur, acur, bcur, mask, i, B, S, tk, dob,
                                       idxcur, BAo, STo, parent, posb, lrid, rrid,
                                       anxt, bnxt, wnxt, S - 1, (i < 29) ? 1 : 0);
        k_gemm1<1><<<dim3(CHID/64, NB/64), 256, 0, stream>>>(
            cha, cla, Wc1th, Wc1tl, bc1, Hh, Hl, lrid, rrid, nullptr, CHID);
        k_gemm<0><<<dim3(CHID/128, NB/128, ZSPLIT), 512, 0, stream>>>(
            Hh, Hl, Wc2th, Wc2tl, bc2, Pb, NB, CHID, CHID, CHID/ZSPLIT);
        k_compose<<<NB, 256, 0, stream>>>(Pb, cha, cla, lrid, rrid, parent, posb,
                                          idxcur, BAo, STo, mask, i, 31 - i,
                                          g2, b2, cha, cla, newbase, idxnxt,
                                          0, nullptr);
        if (i < 29)
            k_wscore<1><<<dim3(NB*2/64, 8), 256, 0, stream>>>(
                cha, cla, posb, idxnxt, Wd1th, Wd1tl, bd1, Wd2, bd2, wnxt, S - 1);
        idxcur = idxnxt;
        idxnxt = (idxnxt == idxA) ? idxB : idxA;
        BAo = BEAM; STo = 31;
        float* tp;
        tp = wcur; wcur = wnxt; wnxt = tp;
        tp = acur; acur = anxt; anxt = tp;
        tp = bcur; bcur = bnxt; bnxt = tp;
    }
    // final compose: l,r = table positions 0,1
    k_gemm1<2><<<dim3(CHID/64, NB/64), 256, 0, stream>>>(
        cha, cla, Wc1th, Wc1tl, bc1, Hh, Hl, nullptr, nullptr, idxcur, CHID);
    k_gemm<0><<<dim3(CHID/128, NB/128, ZSPLIT), 512, 0, stream>>>(
        Hh, Hl, Wc2th, Wc2tl, bc2, Pb, NB, CHID, CHID, CHID/ZSPLIT);
    k_compose<<<NB, 256, 0, stream>>>(Pb, cha, cla, nullptr, nullptr, parent, posb,
                                      idxcur, BEAM, 31, mask, 30, 0,
                                      g2, b2, nullptr, nullptr, 0,
                                      nullptr, 1, nvb);
    k_final<<<NN, 256, 0, stream>>>(nvb, cha, cla, idxcur, mask, acur, bcur, out);
}